// Round 2
// baseline (2093.128 us; speedup 1.0000x reference)
//
#include <hip/hip_runtime.h>
#include <stdint.h>

typedef unsigned int u32;
typedef unsigned long long u64;

#define B_ 8
#define N_ 100000
#define C_ 10
#define K1_ 1000
#define N2_ (C_ * K1_)
#define NBIN 4096
#define CAP 4096       // fallback / topk2 sort capacity
#define CAP_C 2048     // fast-path candidate capacity per slice
#define MIN_CONF_F 0.05f
#define NMS_IOU_F 0.4f
#define POST_IOU_F 0.65f
#define T0_F 0.985f    // conservative fast-path threshold (count ~1500 +/- 38)

#define TOTAL_F4 (B_ * N_ * C_ / 4)  // 2,000,000 float4s

static __device__ __forceinline__ u32 next_pow2_ge(u32 x, u32 lo, u32 hi) {
  u32 n = lo;
  while (n < x && n < hi) n <<= 1;
  return n;
}

// ---------------------------------------------------------------------------
// Init: zero per-slice counters + fallback flags (ws is poisoned 0xAA).
// ---------------------------------------------------------------------------
__global__ void k_init(u32* __restrict__ cnt, u32* __restrict__ flag) {
  int t = threadIdx.x;
  if (t < B_ * C_) { cnt[t] = 0; flag[t] = 0; }
}

// ---------------------------------------------------------------------------
// Fast path pass 1: coalesced float4 scan of all scores; compact s >= T0
// into per-slice candidate buffers via global atomics.
// ---------------------------------------------------------------------------
__global__ __launch_bounds__(256) void k_compact(const float* __restrict__ cls,
                                                 u64* __restrict__ cand,
                                                 u32* __restrict__ cnt) {
  const float4* p4 = (const float4*)cls;
  for (u32 f = blockIdx.x * blockDim.x + threadIdx.x; f < TOTAL_F4;
       f += gridDim.x * blockDim.x) {
    float4 v = p4[f];
    u32 e = f * 4u;
    float vs[4] = {v.x, v.y, v.z, v.w};
#pragma unroll
    for (int j = 0; j < 4; ++j) {
      float s = vs[j];
      if (s >= T0_F) {
        u32 g = e + (u32)j;
        u32 bi = g / (u32)(N_ * C_);
        u32 r = g - bi * (u32)(N_ * C_);
        u32 c = r % (u32)C_;
        u32 i = r / (u32)C_;
        u32 slice = bi * (u32)C_ + c;
        u32 pos = atomicAdd(&cnt[slice], 1u);
        if (pos < CAP_C)
          cand[(size_t)slice * CAP_C + pos] =
              ((u64)__float_as_uint(s) << 32) | (u32)(~i);
      }
    }
  }
}

// ---------------------------------------------------------------------------
// Fast path pass 2: per-slice adaptive bitonic sort of candidates, emit top
// 1000 (stable: value desc, idx asc). Flags slice for fallback if count is
// out of [K1, CAP_C].
// ---------------------------------------------------------------------------
__global__ __launch_bounds__(256) void k_sel(const u64* __restrict__ cand,
                                             const u32* __restrict__ cnt,
                                             u32* __restrict__ flag,
                                             float* __restrict__ score1,
                                             int* __restrict__ idx1) {
  const int slice = blockIdx.x;
  const int tid = threadIdx.x, bd = blockDim.x;
  __shared__ u64 buf[CAP_C];

  u32 m = cnt[slice];
  if (m < (u32)K1_ || m > (u32)CAP_C) {
    if (tid == 0) flag[slice] = 1;
    return;
  }
  const u32 n = next_pow2_ge(m, 1024u, (u32)CAP_C);

  for (u32 i = tid; i < n; i += bd)
    buf[i] = (i < m) ? cand[(size_t)slice * CAP_C + i] : 0ull;
  __syncthreads();

  for (u32 kk = 2; kk <= n; kk <<= 1) {
    for (u32 j = kk >> 1; j > 0; j >>= 1) {
      for (u32 i = tid; i < n; i += bd) {
        u32 l = i ^ j;
        if (l > i) {
          u64 a = buf[i], bb = buf[l];
          bool desc = ((i & kk) == 0);
          if (desc ? (a < bb) : (a > bb)) { buf[i] = bb; buf[l] = a; }
        }
      }
      __syncthreads();
    }
  }

  for (int p = tid; p < K1_; p += bd) {
    u64 e = buf[p];
    u32 k = (u32)(e >> 32);
    score1[slice * K1_ + p] = __uint_as_float(k);
    idx1[slice * K1_ + p] = (int)(~(u32)e);
  }
}

// ---------------------------------------------------------------------------
// Fallback (exact, slow) per-slice top-1000 — only runs for flagged slices.
// Two-level histogram radix-select + bitonic sort. Guarantees exactness when
// the fixed-threshold fast path can't.
// ---------------------------------------------------------------------------
__global__ __launch_bounds__(256) void k_topk1_fb(const float* __restrict__ cls,
                                                  const u32* __restrict__ flag,
                                                  float* __restrict__ score1,
                                                  int* __restrict__ idx1) {
  const int slice = blockIdx.x;
  if (!flag[slice]) return;
  const int b = slice / C_, c = slice % C_;
  const int tid = threadIdx.x, bd = blockDim.x;

  __shared__ u32 hist[NBIN];
  __shared__ u64 buf[CAP];
  __shared__ int sh_b1;
  __shared__ u32 sh_base, sh_T, sh_cnt;

  for (int i = tid; i < NBIN; i += bd) hist[i] = 0;
  __syncthreads();
  for (int i = tid; i < N_; i += bd) {
    float s = cls[((size_t)b * N_ + i) * C_ + c];
    if (s >= MIN_CONF_F) atomicAdd(&hist[__float_as_uint(s) >> 19], 1u);
  }
  __syncthreads();
  if (tid == 0) {
    u32 cum = 0; int b1 = -1; u32 base = 0;
    for (int bin = NBIN - 1; bin >= 0; --bin) {
      cum += hist[bin];
      if (cum >= (u32)K1_) { b1 = bin; base = cum - hist[bin]; break; }
    }
    sh_b1 = b1; sh_base = base;
    if (b1 < 0) sh_T = 0;
  }
  __syncthreads();
  const int b1 = sh_b1;

  if (b1 >= 0) {
    const u32 base = sh_base;
    for (int i = tid; i < NBIN; i += bd) hist[i] = 0;
    __syncthreads();
    for (int i = tid; i < N_; i += bd) {
      float s = cls[((size_t)b * N_ + i) * C_ + c];
      if (s >= MIN_CONF_F) {
        u32 k = __float_as_uint(s);
        if ((int)(k >> 19) == b1) atomicAdd(&hist[(k >> 7) & 0xFFFu], 1u);
      }
    }
    __syncthreads();
    if (tid == 0) {
      u32 cum = base;
      u32 T = ((u32)b1) << 19;
      for (int bin = NBIN - 1; bin >= 0; --bin) {
        cum += hist[bin];
        if (cum >= (u32)K1_) { T = (((u32)b1) << 19) | (((u32)bin) << 7); break; }
      }
      sh_T = T;
    }
    __syncthreads();
  }

  if (tid == 0) sh_cnt = 0;
  __syncthreads();
  const u32 T = sh_T;
  for (int i = tid; i < N_; i += bd) {
    float s = cls[((size_t)b * N_ + i) * C_ + c];
    if (s >= MIN_CONF_F) {
      u32 k = __float_as_uint(s);
      if (k >= T) {
        u32 pos = atomicAdd(&sh_cnt, 1u);
        if (pos < CAP) buf[pos] = ((u64)k << 32) | (u32)(~(u32)i);
      }
    }
  }
  __syncthreads();
  u32 m = sh_cnt; if (m > CAP) m = CAP;
  for (int i = tid; i < CAP; i += bd)
    if ((u32)i >= m) buf[i] = 0ull;
  __syncthreads();

  for (u32 kk = 2; kk <= CAP; kk <<= 1) {
    for (u32 j = kk >> 1; j > 0; j >>= 1) {
      for (u32 i = tid; i < CAP; i += bd) {
        u32 l = i ^ j;
        if (l > i) {
          u64 a = buf[i], bb = buf[l];
          bool desc = ((i & kk) == 0);
          if (desc ? (a < bb) : (a > bb)) { buf[i] = bb; buf[l] = a; }
        }
      }
      __syncthreads();
    }
  }

  for (int p = tid; p < K1_; p += bd) {
    u64 e = buf[p];
    u32 k = (u32)(e >> 32);
    float s; int oi;
    if (k == 0) { s = -1.0f; oi = 0; }
    else { s = __uint_as_float(k); oi = (int)(~(u32)e); }
    score1[slice * K1_ + p] = s;
    idx1[slice * K1_ + p] = oi;
  }
}

// ---------------------------------------------------------------------------
// Kernel 2: per-(b,c) greedy NMS @ 0.4 (ballot-based suppression masks).
// ---------------------------------------------------------------------------
__global__ __launch_bounds__(256) void k_nms1(const float* __restrict__ boxes,
                                              const float* __restrict__ score1,
                                              const int* __restrict__ idx1,
                                              int* __restrict__ keep1) {
  const int slice = blockIdx.x;
  const int b = slice / C_;
  const int tid = threadIdx.x;

  __shared__ float sy1[1024], sx1[1024], sy2[1024], sx2[1024], sar[1024];
  __shared__ u64 valid64[16], supp64[16];
  if (tid < 16) supp64[tid] = 0;

  for (int p = tid; p < 1024; p += 256) {
    float s = (p < K1_) ? score1[slice * K1_ + p] : -1.0f;
    bool v = (s >= MIN_CONF_F);
    float cx = 0.f, cy = 0.f, w = 0.f, h = 0.f;
    if (v) {
      int oi = idx1[slice * K1_ + p];
      const float4 bp = *(const float4*)(boxes + ((size_t)b * N_ + oi) * 4);
      cx = bp.x; cy = bp.y; w = bp.z; h = bp.w;
    }
    float y1 = cy - h * 0.5f, x1 = cx - w * 0.5f;
    float y2 = cy + h * 0.5f, x2 = cx + w * 0.5f;
    sy1[p] = y1; sx1[p] = x1; sy2[p] = y2; sx2[p] = x2;
    sar[p] = (y2 - y1) * (x2 - x1);
    u64 mb = __ballot(v);
    if ((tid & 63) == 0) valid64[p >> 6] = mb;
  }
  __syncthreads();

  for (int i = 0; i < K1_; ++i) {
    u64 vb = valid64[i >> 6], sb = supp64[i >> 6];
    bool active = ((vb >> (i & 63)) & 1ull) && !((sb >> (i & 63)) & 1ull);
    if (!active) continue;
    float iy1 = sy1[i], ix1 = sx1[i], iy2 = sy2[i], ix2 = sx2[i], ia = sar[i];
    for (int p = tid; p < 1024; p += 256) {
      float ih = fminf(iy2, sy2[p]) - fmaxf(iy1, sy1[p]); ih = fmaxf(ih, 0.0f);
      float iw = fminf(ix2, sx2[p]) - fmaxf(ix1, sx1[p]); iw = fmaxf(iw, 0.0f);
      float inter = ih * iw;
      float uni = (ia + sar[p]) - inter;
      float iou = inter / fmaxf(uni, 1e-8f);
      bool pred = (p > i) && (iou > NMS_IOU_F);
      u64 mb = __ballot(pred);
      if (((tid & 63) == 0) && mb) atomicOr(&supp64[p >> 6], mb);
    }
    __syncthreads();
  }

  for (int p = tid; p < K1_; p += 256) {
    bool keep = ((valid64[p >> 6] >> (p & 63)) & 1ull) &&
                !((supp64[p >> 6] >> (p & 63)) & 1ull);
    keep1[slice * K1_ + p] = keep ? 1 : 0;
  }
}

// ---------------------------------------------------------------------------
// Kernel 3: per-batch top-1000 over the C*K1 survivors (stable, flat-index
// tie-break). Histogram select + adaptive bitonic.
// ---------------------------------------------------------------------------
__global__ __launch_bounds__(256) void k_topk2(const float* __restrict__ score1,
                                               const int* __restrict__ idx1,
                                               const int* __restrict__ keep1,
                                               float* __restrict__ sel_score,
                                               int* __restrict__ sel_cls,
                                               int* __restrict__ sel_orig) {
  const int b = blockIdx.x;
  const int tid = threadIdx.x, bd = blockDim.x;

  __shared__ u32 hist[NBIN];
  __shared__ u64 buf[CAP];
  __shared__ int sh_b1;
  __shared__ u32 sh_base, sh_T, sh_cnt;

  for (int i = tid; i < NBIN; i += bd) hist[i] = 0;
  __syncthreads();
  for (int f = tid; f < N2_; f += bd) {
    if (keep1[b * N2_ + f])
      atomicAdd(&hist[__float_as_uint(score1[b * N2_ + f]) >> 19], 1u);
  }
  __syncthreads();
  if (tid == 0) {
    u32 cum = 0; int b1 = -1; u32 base = 0;
    for (int bin = NBIN - 1; bin >= 0; --bin) {
      cum += hist[bin];
      if (cum >= (u32)K1_) { b1 = bin; base = cum - hist[bin]; break; }
    }
    sh_b1 = b1; sh_base = base;
    if (b1 < 0) sh_T = 0;
  }
  __syncthreads();
  const int b1 = sh_b1;

  if (b1 >= 0) {
    const u32 base = sh_base;
    for (int i = tid; i < NBIN; i += bd) hist[i] = 0;
    __syncthreads();
    for (int f = tid; f < N2_; f += bd) {
      if (keep1[b * N2_ + f]) {
        u32 k = __float_as_uint(score1[b * N2_ + f]);
        if ((int)(k >> 19) == b1) atomicAdd(&hist[(k >> 7) & 0xFFFu], 1u);
      }
    }
    __syncthreads();
    if (tid == 0) {
      u32 cum = base;
      u32 T = ((u32)b1) << 19;
      for (int bin = NBIN - 1; bin >= 0; --bin) {
        cum += hist[bin];
        if (cum >= (u32)K1_) { T = (((u32)b1) << 19) | (((u32)bin) << 7); break; }
      }
      sh_T = T;
    }
    __syncthreads();
  }

  if (tid == 0) sh_cnt = 0;
  __syncthreads();
  const u32 T = sh_T;
  for (int f = tid; f < N2_; f += bd) {
    if (keep1[b * N2_ + f]) {
      u32 k = __float_as_uint(score1[b * N2_ + f]);
      if (k >= T) {
        u32 pos = atomicAdd(&sh_cnt, 1u);
        if (pos < CAP) buf[pos] = ((u64)k << 32) | (u32)(~(u32)f);
      }
    }
  }
  __syncthreads();
  u32 m = sh_cnt; if (m > CAP) m = CAP;
  const u32 n = next_pow2_ge(m, 1024u, (u32)CAP);
  for (u32 i = tid; i < n; i += bd)
    if (i >= m) buf[i] = 0ull;
  __syncthreads();

  for (u32 kk = 2; kk <= n; kk <<= 1) {
    for (u32 j = kk >> 1; j > 0; j >>= 1) {
      for (u32 i = tid; i < n; i += bd) {
        u32 l = i ^ j;
        if (l > i) {
          u64 a = buf[i], bb = buf[l];
          bool desc = ((i & kk) == 0);
          if (desc ? (a < bb) : (a > bb)) { buf[i] = bb; buf[l] = a; }
        }
      }
      __syncthreads();
    }
  }

  for (int p = tid; p < K1_; p += bd) {
    u64 e = buf[p];
    u32 k = (u32)(e >> 32);
    float s; int cls, orig;
    if (k == 0) { s = -1.0f; cls = 0; orig = 0; }
    else {
      s = __uint_as_float(k);
      u32 f = ~(u32)e;
      cls = (int)(f / K1_);
      int slot = (int)(f - (u32)cls * K1_);
      orig = idx1[(b * C_ + cls) * K1_ + slot];
    }
    sel_score[b * K1_ + p] = s;
    sel_cls[b * K1_ + p] = cls;
    sel_orig[b * K1_ + p] = orig;
  }
}

// ---------------------------------------------------------------------------
// Kernel 4: per-batch class-agnostic NMS @ 0.65, stable compaction of kept
// rows, zero-fill, final (8,1000,6) write.
// ---------------------------------------------------------------------------
__global__ __launch_bounds__(256) void k_nms2_out(const float* __restrict__ boxes,
                                                  const float* __restrict__ sel_score,
                                                  const int* __restrict__ sel_cls,
                                                  const int* __restrict__ sel_orig,
                                                  float* __restrict__ out) {
  const int b = blockIdx.x;
  const int tid = threadIdx.x;

  __shared__ float sy1[1024], sx1[1024], sy2[1024], sx2[1024], sar[1024];
  __shared__ float rcx[K1_], rcy[K1_], rw[K1_], rh[K1_], rs[K1_];
  __shared__ int rcls[K1_];
  __shared__ u64 valid64[16], supp64[16];
  __shared__ int ordc;
  __shared__ short ord[K1_];

  if (tid < 16) supp64[tid] = 0;

  for (int p = tid; p < 1024; p += 256) {
    float s = (p < K1_) ? sel_score[b * K1_ + p] : -1.0f;
    bool v = (s >= MIN_CONF_F);
    float cx = 0.f, cy = 0.f, w = 0.f, h = 0.f;
    if (v) {
      int oi = sel_orig[b * K1_ + p];
      const float4 bp = *(const float4*)(boxes + ((size_t)b * N_ + oi) * 4);
      cx = bp.x; cy = bp.y; w = bp.z; h = bp.w;
    }
    float y1 = cy - h * 0.5f, x1 = cx - w * 0.5f;
    float y2 = cy + h * 0.5f, x2 = cx + w * 0.5f;
    sy1[p] = y1; sx1[p] = x1; sy2[p] = y2; sx2[p] = x2;
    sar[p] = (y2 - y1) * (x2 - x1);
    if (p < K1_) {
      rcx[p] = cx; rcy[p] = cy; rw[p] = w; rh[p] = h;
      rs[p] = s;
      rcls[p] = sel_cls[b * K1_ + p];
    }
    u64 mb = __ballot(v);
    if ((tid & 63) == 0) valid64[p >> 6] = mb;
  }
  __syncthreads();

  for (int i = 0; i < K1_; ++i) {
    u64 vb = valid64[i >> 6], sb = supp64[i >> 6];
    bool active = ((vb >> (i & 63)) & 1ull) && !((sb >> (i & 63)) & 1ull);
    if (!active) continue;
    float iy1 = sy1[i], ix1 = sx1[i], iy2 = sy2[i], ix2 = sx2[i], ia = sar[i];
    for (int p = tid; p < 1024; p += 256) {
      float ih = fminf(iy2, sy2[p]) - fmaxf(iy1, sy1[p]); ih = fmaxf(ih, 0.0f);
      float iw = fminf(ix2, sx2[p]) - fmaxf(ix1, sx1[p]); iw = fmaxf(iw, 0.0f);
      float inter = ih * iw;
      float uni = (ia + sar[p]) - inter;
      float iou = inter / fmaxf(uni, 1e-8f);
      bool pred = (p > i) && (iou > POST_IOU_F);
      u64 mb = __ballot(pred);
      if (((tid & 63) == 0) && mb) atomicOr(&supp64[p >> 6], mb);
    }
    __syncthreads();
  }

  if (tid == 0) {
    int cnt = 0;
    for (int p = 0; p < K1_; ++p) {
      bool keep = ((valid64[p >> 6] >> (p & 63)) & 1ull) &&
                  !((supp64[p >> 6] >> (p & 63)) & 1ull);
      if (keep) ord[cnt++] = (short)p;
    }
    ordc = cnt;
  }
  __syncthreads();

  for (int t = tid; t < K1_ * 6; t += 256) out[(size_t)b * K1_ * 6 + t] = 0.0f;
  __syncthreads();

  const int cnt = ordc;
  for (int q = tid; q < cnt; q += 256) {
    int p = ord[q];
    float* o = out + ((size_t)b * K1_ + q) * 6;
    o[0] = rcx[p]; o[1] = rcy[p]; o[2] = rw[p]; o[3] = rh[p];
    o[4] = (float)rcls[p];
    o[5] = rs[p];
  }
}

// ---------------------------------------------------------------------------
extern "C" void kernel_launch(void* const* d_in, const int* in_sizes, int n_in,
                              void* d_out, int out_size, void* d_ws, size_t ws_size,
                              hipStream_t stream) {
  const float* cls = (const float*)d_in[0];    // (8,100000,10) f32
  const float* boxes = (const float*)d_in[1];  // (8,100000,4)  f32
  float* out = (float*)d_out;                  // (8,1000,6)    f32

  char* ws = (char*)d_ws;
  float* score1    = (float*)(ws);                     // 80000 f32
  int*   idx1      = (int*)(ws + 320000);              // 80000 i32
  int*   keep1     = (int*)(ws + 640000);              // 80000 i32
  float* sel_score = (float*)(ws + 960000);            // 8000 f32
  int*   sel_cls   = (int*)(ws + 992000);              // 8000 i32
  int*   sel_orig  = (int*)(ws + 1024000);             // 8000 i32
  u32*   cnt       = (u32*)(ws + 1056000);             // 80 u32
  u32*   flag      = (u32*)(ws + 1056320);             // 80 u32
  u64*   cand      = (u64*)(ws + 1056640);             // 80*2048 u64 = 1.31 MB

  hipLaunchKernelGGL(k_init, dim3(1), dim3(256), 0, stream, cnt, flag);
  hipLaunchKernelGGL(k_compact, dim3(2048), dim3(256), 0, stream,
                     cls, cand, cnt);
  hipLaunchKernelGGL(k_sel, dim3(B_ * C_), dim3(256), 0, stream,
                     cand, cnt, flag, score1, idx1);
  hipLaunchKernelGGL(k_topk1_fb, dim3(B_ * C_), dim3(256), 0, stream,
                     cls, flag, score1, idx1);
  hipLaunchKernelGGL(k_nms1, dim3(B_ * C_), dim3(256), 0, stream,
                     boxes, score1, idx1, keep1);
  hipLaunchKernelGGL(k_topk2, dim3(B_), dim3(256), 0, stream,
                     score1, idx1, keep1, sel_score, sel_cls, sel_orig);
  hipLaunchKernelGGL(k_nms2_out, dim3(B_), dim3(256), 0, stream,
                     boxes, sel_score, sel_cls, sel_orig, out);
}

// Round 3
// 1667.422 us; speedup vs baseline: 1.2553x; 1.2553x over previous
//
#include <hip/hip_runtime.h>
#include <stdint.h>

typedef unsigned int u32;
typedef unsigned long long u64;

#define B_ 8
#define N_ 100000
#define C_ 10
#define K1_ 1000
#define N2_ (C_ * K1_)
#define NBIN 4096
#define CAP 4096       // fallback / topk2 sort capacity
#define CAP_C 2048     // fast-path candidate capacity per slice
#define SEGROWS 256    // NMS mask segment rows (4 segments cover 1000)
#define MIN_CONF_F 0.05f
#define NMS_IOU_F 0.4f
#define POST_IOU_F 0.65f
#define T0_F 0.985f    // conservative fast-path threshold (count ~1500 +/- 38)

#define TOTAL_F4 (B_ * N_ * C_ / 4)  // 2,000,000 float4s

static __device__ __forceinline__ u32 next_pow2_ge(u32 x, u32 lo, u32 hi) {
  u32 n = lo;
  while (n < x && n < hi) n <<= 1;
  return n;
}

// ---------------------------------------------------------------------------
// Init: zero per-slice counters + fallback flags (ws is poisoned 0xAA).
// ---------------------------------------------------------------------------
__global__ void k_init(u32* __restrict__ cnt, u32* __restrict__ flag) {
  int t = threadIdx.x;
  if (t < B_ * C_) { cnt[t] = 0; flag[t] = 0; }
}

// ---------------------------------------------------------------------------
// Fast path pass 1: coalesced float4 scan of all scores; compact s >= T0
// into per-slice candidate buffers via global atomics.
// ---------------------------------------------------------------------------
__global__ __launch_bounds__(256) void k_compact(const float* __restrict__ cls,
                                                 u64* __restrict__ cand,
                                                 u32* __restrict__ cnt) {
  const float4* p4 = (const float4*)cls;
  for (u32 f = blockIdx.x * blockDim.x + threadIdx.x; f < TOTAL_F4;
       f += gridDim.x * blockDim.x) {
    float4 v = p4[f];
    u32 e = f * 4u;
    float vs[4] = {v.x, v.y, v.z, v.w};
#pragma unroll
    for (int j = 0; j < 4; ++j) {
      float s = vs[j];
      if (s >= T0_F) {
        u32 g = e + (u32)j;
        u32 bi = g / (u32)(N_ * C_);
        u32 r = g - bi * (u32)(N_ * C_);
        u32 c = r % (u32)C_;
        u32 i = r / (u32)C_;
        u32 slice = bi * (u32)C_ + c;
        u32 pos = atomicAdd(&cnt[slice], 1u);
        if (pos < CAP_C)
          cand[(size_t)slice * CAP_C + pos] =
              ((u64)__float_as_uint(s) << 32) | (u32)(~i);
      }
    }
  }
}

// ---------------------------------------------------------------------------
// Fast path pass 2: per-slice adaptive bitonic sort of candidates, emit top
// 1000 (stable: value desc, idx asc). Flags slice for fallback if count is
// out of [K1, CAP_C].
// ---------------------------------------------------------------------------
__global__ __launch_bounds__(256) void k_sel(const u64* __restrict__ cand,
                                             const u32* __restrict__ cnt,
                                             u32* __restrict__ flag,
                                             float* __restrict__ score1,
                                             int* __restrict__ idx1) {
  const int slice = blockIdx.x;
  const int tid = threadIdx.x, bd = blockDim.x;
  __shared__ u64 buf[CAP_C];

  u32 m = cnt[slice];
  if (m < (u32)K1_ || m > (u32)CAP_C) {
    if (tid == 0) flag[slice] = 1;
    return;
  }
  const u32 n = next_pow2_ge(m, 1024u, (u32)CAP_C);

  for (u32 i = tid; i < n; i += bd)
    buf[i] = (i < m) ? cand[(size_t)slice * CAP_C + i] : 0ull;
  __syncthreads();

  for (u32 kk = 2; kk <= n; kk <<= 1) {
    for (u32 j = kk >> 1; j > 0; j >>= 1) {
      for (u32 i = tid; i < n; i += bd) {
        u32 l = i ^ j;
        if (l > i) {
          u64 a = buf[i], bb = buf[l];
          bool desc = ((i & kk) == 0);
          if (desc ? (a < bb) : (a > bb)) { buf[i] = bb; buf[l] = a; }
        }
      }
      __syncthreads();
    }
  }

  for (int p = tid; p < K1_; p += bd) {
    u64 e = buf[p];
    u32 k = (u32)(e >> 32);
    score1[slice * K1_ + p] = __uint_as_float(k);
    idx1[slice * K1_ + p] = (int)(~(u32)e);
  }
}

// ---------------------------------------------------------------------------
// Fallback (exact, slow) per-slice top-1000 — only runs for flagged slices.
// ---------------------------------------------------------------------------
__global__ __launch_bounds__(256) void k_topk1_fb(const float* __restrict__ cls,
                                                  const u32* __restrict__ flag,
                                                  float* __restrict__ score1,
                                                  int* __restrict__ idx1) {
  const int slice = blockIdx.x;
  if (!flag[slice]) return;
  const int b = slice / C_, c = slice % C_;
  const int tid = threadIdx.x, bd = blockDim.x;

  __shared__ u32 hist[NBIN];
  __shared__ u64 buf[CAP];
  __shared__ int sh_b1;
  __shared__ u32 sh_base, sh_T, sh_cnt;

  for (int i = tid; i < NBIN; i += bd) hist[i] = 0;
  __syncthreads();
  for (int i = tid; i < N_; i += bd) {
    float s = cls[((size_t)b * N_ + i) * C_ + c];
    if (s >= MIN_CONF_F) atomicAdd(&hist[__float_as_uint(s) >> 19], 1u);
  }
  __syncthreads();
  if (tid == 0) {
    u32 cum = 0; int b1 = -1; u32 base = 0;
    for (int bin = NBIN - 1; bin >= 0; --bin) {
      cum += hist[bin];
      if (cum >= (u32)K1_) { b1 = bin; base = cum - hist[bin]; break; }
    }
    sh_b1 = b1; sh_base = base;
    if (b1 < 0) sh_T = 0;
  }
  __syncthreads();
  const int b1 = sh_b1;

  if (b1 >= 0) {
    const u32 base = sh_base;
    for (int i = tid; i < NBIN; i += bd) hist[i] = 0;
    __syncthreads();
    for (int i = tid; i < N_; i += bd) {
      float s = cls[((size_t)b * N_ + i) * C_ + c];
      if (s >= MIN_CONF_F) {
        u32 k = __float_as_uint(s);
        if ((int)(k >> 19) == b1) atomicAdd(&hist[(k >> 7) & 0xFFFu], 1u);
      }
    }
    __syncthreads();
    if (tid == 0) {
      u32 cum = base;
      u32 T = ((u32)b1) << 19;
      for (int bin = NBIN - 1; bin >= 0; --bin) {
        cum += hist[bin];
        if (cum >= (u32)K1_) { T = (((u32)b1) << 19) | (((u32)bin) << 7); break; }
      }
      sh_T = T;
    }
    __syncthreads();
  }

  if (tid == 0) sh_cnt = 0;
  __syncthreads();
  const u32 T = sh_T;
  for (int i = tid; i < N_; i += bd) {
    float s = cls[((size_t)b * N_ + i) * C_ + c];
    if (s >= MIN_CONF_F) {
      u32 k = __float_as_uint(s);
      if (k >= T) {
        u32 pos = atomicAdd(&sh_cnt, 1u);
        if (pos < CAP) buf[pos] = ((u64)k << 32) | (u32)(~(u32)i);
      }
    }
  }
  __syncthreads();
  u32 m = sh_cnt; if (m > CAP) m = CAP;
  for (int i = tid; i < CAP; i += bd)
    if ((u32)i >= m) buf[i] = 0ull;
  __syncthreads();

  for (u32 kk = 2; kk <= CAP; kk <<= 1) {
    for (u32 j = kk >> 1; j > 0; j >>= 1) {
      for (u32 i = tid; i < CAP; i += bd) {
        u32 l = i ^ j;
        if (l > i) {
          u64 a = buf[i], bb = buf[l];
          bool desc = ((i & kk) == 0);
          if (desc ? (a < bb) : (a > bb)) { buf[i] = bb; buf[l] = a; }
        }
      }
      __syncthreads();
    }
  }

  for (int p = tid; p < K1_; p += bd) {
    u64 e = buf[p];
    u32 k = (u32)(e >> 32);
    float s; int oi;
    if (k == 0) { s = -1.0f; oi = 0; }
    else { s = __uint_as_float(k); oi = (int)(~(u32)e); }
    score1[slice * K1_ + p] = s;
    idx1[slice * K1_ + p] = oi;
  }
}

// ---------------------------------------------------------------------------
// NMS core: parallel pairwise-mask build (4 segments of 256 rows in LDS) +
// single-wave barrier-free greedy bit-scan. 1024 threads.
// keepw[16] (u64 bitmask) is the result; caller must __syncthreads() after.
// ---------------------------------------------------------------------------
__device__ __forceinline__ void nms_run(const float* __restrict__ scores,
                                        const int* __restrict__ origs,
                                        const float* __restrict__ boxesB,
                                        float thr,
                                        float4* box4, float* area,
                                        u64* mask, u64* validw, u64* keepw) {
  const int tid = threadIdx.x;
  const int wave = tid >> 6, lane = tid & 63;

  // ---- load boxes -> corners + areas; valid bitmask ----
  {
    const int p = tid;  // 1024 threads, one element each
    float s = (p < K1_) ? scores[p] : -1.0f;
    bool v = (s >= MIN_CONF_F);
    float cx = 0.f, cy = 0.f, w = 0.f, h = 0.f;
    if (v) {
      const float4 bp = *(const float4*)(boxesB + (size_t)origs[p] * 4);
      cx = bp.x; cy = bp.y; w = bp.z; h = bp.w;
    }
    float y1 = cy - h * 0.5f, x1 = cx - w * 0.5f;
    float y2 = cy + h * 0.5f, x2 = cx + w * 0.5f;
    box4[p] = make_float4(y1, x1, y2, x2);
    area[p] = (y2 - y1) * (x2 - x1);
    u64 mb = __ballot(v);
    if (lane == 0) validw[wave] = mb;
  }
  __syncthreads();

  u64 vw = validw[tid & 15];  // lanes 16-63 mirror lane&15 (harmless)
  u64 supp = 0;

  for (int seg = 0; seg < 4; ++seg) {
    const int ibase = seg * SEGROWS;
    const int lim = (K1_ - ibase < SEGROWS) ? (K1_ - ibase) : SEGROWS;

    // ---- build mask rows [ibase, ibase+lim) : 16 waves x balanced tasks ----
    for (int t = wave; t < SEGROWS * 16; t += 16) {
      const int il = t & (SEGROWS - 1);
      const int w = t >> 8;  // word index 0..15 (SEGROWS == 256)
      if (il >= lim) continue;                 // wave-uniform
      const int i = ibase + il;
      u64 m = 0;
      if (w >= (i >> 6)) {                     // triangular: skip all-zero words
        const int j = (w << 6) | lane;
        float4 jb = box4[j];
        float ja = area[j];
        float4 ib = box4[i];   // broadcast
        float ia = area[i];
        float ih = fminf(ib.z, jb.z) - fmaxf(ib.x, jb.x); ih = fmaxf(ih, 0.0f);
        float iw_ = fminf(ib.w, jb.w) - fmaxf(ib.y, jb.y); iw_ = fmaxf(iw_, 0.0f);
        float inter = ih * iw_;
        float uni = (ia + ja) - inter;
        float iou = inter / fmaxf(uni, 1e-8f);
        m = __ballot((iou > thr) && (j > i));
      }
      if (lane == 0) mask[il * 16 + w] = m;
    }
    __syncthreads();

    // ---- serial greedy scan over this segment: wave 0 only, no barriers ----
    if (tid < 64) {
      const int l = tid & 15;
      u64 r0 = mask[0 * 16 + l];
      u64 r1 = mask[1 * 16 + l];
      u64 r2 = mask[2 * 16 + l];
      u64 r3 = mask[3 * 16 + l];
      for (int il = 0; il < lim; il += 4) {  // lim % 4 == 0 (256 or 232)
        const int i0 = ibase + il;
        const int n0 = (il + 4 < lim) ? il + 4 : il;
        const int n1 = (il + 5 < lim) ? il + 5 : il;
        const int n2 = (il + 6 < lim) ? il + 6 : il;
        const int n3 = (il + 7 < lim) ? il + 7 : il;
        u64 m0 = r0, m1 = r1, m2 = r2, m3 = r3;
        r0 = mask[n0 * 16 + l];
        r1 = mask[n1 * 16 + l];
        r2 = mask[n2 * 16 + l];
        r3 = mask[n3 * 16 + l];
        bool a;
        a = (tid == (i0 >> 6)) && (((vw & ~supp) >> (i0 & 63)) & 1ull);
        if (__any(a)) supp |= m0;
        a = (tid == ((i0 + 1) >> 6)) && (((vw & ~supp) >> ((i0 + 1) & 63)) & 1ull);
        if (__any(a)) supp |= m1;
        a = (tid == ((i0 + 2) >> 6)) && (((vw & ~supp) >> ((i0 + 2) & 63)) & 1ull);
        if (__any(a)) supp |= m2;
        a = (tid == ((i0 + 3) >> 6)) && (((vw & ~supp) >> ((i0 + 3) & 63)) & 1ull);
        if (__any(a)) supp |= m3;
      }
    }
    __syncthreads();
  }

  if (tid < 16) keepw[tid] = vw & ~supp;  // lanes 0-15 of wave 0 hold the state
}

// ---------------------------------------------------------------------------
// Kernel 2: per-(b,c) greedy NMS @ 0.4.
// ---------------------------------------------------------------------------
__global__ __launch_bounds__(1024) void k_nms1(const float* __restrict__ boxes,
                                               const float* __restrict__ score1,
                                               const int* __restrict__ idx1,
                                               int* __restrict__ keep1) {
  __shared__ float4 box4[1024];
  __shared__ float area[1024];
  __shared__ u64 mask[SEGROWS * 16];
  __shared__ u64 validw[16], keepw[16];

  const int slice = blockIdx.x;
  const int b = slice / C_;
  nms_run(score1 + slice * K1_, idx1 + slice * K1_,
          boxes + (size_t)b * N_ * 4, NMS_IOU_F,
          box4, area, mask, validw, keepw);
  __syncthreads();

  const int p = threadIdx.x;
  if (p < K1_)
    keep1[slice * K1_ + p] = (int)((keepw[p >> 6] >> (p & 63)) & 1ull);
}

// ---------------------------------------------------------------------------
// Kernel 3: per-batch top-1000 over the C*K1 survivors (stable, flat-index
// tie-break). Histogram select + adaptive bitonic.
// ---------------------------------------------------------------------------
__global__ __launch_bounds__(256) void k_topk2(const float* __restrict__ score1,
                                               const int* __restrict__ idx1,
                                               const int* __restrict__ keep1,
                                               float* __restrict__ sel_score,
                                               int* __restrict__ sel_cls,
                                               int* __restrict__ sel_orig) {
  const int b = blockIdx.x;
  const int tid = threadIdx.x, bd = blockDim.x;

  __shared__ u32 hist[NBIN];
  __shared__ u64 buf[CAP];
  __shared__ int sh_b1;
  __shared__ u32 sh_base, sh_T, sh_cnt;

  for (int i = tid; i < NBIN; i += bd) hist[i] = 0;
  __syncthreads();
  for (int f = tid; f < N2_; f += bd) {
    if (keep1[b * N2_ + f])
      atomicAdd(&hist[__float_as_uint(score1[b * N2_ + f]) >> 19], 1u);
  }
  __syncthreads();
  if (tid == 0) {
    u32 cum = 0; int b1 = -1; u32 base = 0;
    for (int bin = NBIN - 1; bin >= 0; --bin) {
      cum += hist[bin];
      if (cum >= (u32)K1_) { b1 = bin; base = cum - hist[bin]; break; }
    }
    sh_b1 = b1; sh_base = base;
    if (b1 < 0) sh_T = 0;
  }
  __syncthreads();
  const int b1 = sh_b1;

  if (b1 >= 0) {
    const u32 base = sh_base;
    for (int i = tid; i < NBIN; i += bd) hist[i] = 0;
    __syncthreads();
    for (int f = tid; f < N2_; f += bd) {
      if (keep1[b * N2_ + f]) {
        u32 k = __float_as_uint(score1[b * N2_ + f]);
        if ((int)(k >> 19) == b1) atomicAdd(&hist[(k >> 7) & 0xFFFu], 1u);
      }
    }
    __syncthreads();
    if (tid == 0) {
      u32 cum = base;
      u32 T = ((u32)b1) << 19;
      for (int bin = NBIN - 1; bin >= 0; --bin) {
        cum += hist[bin];
        if (cum >= (u32)K1_) { T = (((u32)b1) << 19) | (((u32)bin) << 7); break; }
      }
      sh_T = T;
    }
    __syncthreads();
  }

  if (tid == 0) sh_cnt = 0;
  __syncthreads();
  const u32 T = sh_T;
  for (int f = tid; f < N2_; f += bd) {
    if (keep1[b * N2_ + f]) {
      u32 k = __float_as_uint(score1[b * N2_ + f]);
      if (k >= T) {
        u32 pos = atomicAdd(&sh_cnt, 1u);
        if (pos < CAP) buf[pos] = ((u64)k << 32) | (u32)(~(u32)f);
      }
    }
  }
  __syncthreads();
  u32 m = sh_cnt; if (m > CAP) m = CAP;
  const u32 n = next_pow2_ge(m, 1024u, (u32)CAP);
  for (u32 i = tid; i < n; i += bd)
    if (i >= m) buf[i] = 0ull;
  __syncthreads();

  for (u32 kk = 2; kk <= n; kk <<= 1) {
    for (u32 j = kk >> 1; j > 0; j >>= 1) {
      for (u32 i = tid; i < n; i += bd) {
        u32 l = i ^ j;
        if (l > i) {
          u64 a = buf[i], bb = buf[l];
          bool desc = ((i & kk) == 0);
          if (desc ? (a < bb) : (a > bb)) { buf[i] = bb; buf[l] = a; }
        }
      }
      __syncthreads();
    }
  }

  for (int p = tid; p < K1_; p += bd) {
    u64 e = buf[p];
    u32 k = (u32)(e >> 32);
    float s; int cls, orig;
    if (k == 0) { s = -1.0f; cls = 0; orig = 0; }
    else {
      s = __uint_as_float(k);
      u32 f = ~(u32)e;
      cls = (int)(f / K1_);
      int slot = (int)(f - (u32)cls * K1_);
      orig = idx1[(b * C_ + cls) * K1_ + slot];
    }
    sel_score[b * K1_ + p] = s;
    sel_cls[b * K1_ + p] = cls;
    sel_orig[b * K1_ + p] = orig;
  }
}

// ---------------------------------------------------------------------------
// Kernel 4: per-batch class-agnostic NMS @ 0.65, stable compaction, output.
// ---------------------------------------------------------------------------
__global__ __launch_bounds__(1024) void k_nms2_out(const float* __restrict__ boxes,
                                                   const float* __restrict__ sel_score,
                                                   const int* __restrict__ sel_cls,
                                                   const int* __restrict__ sel_orig,
                                                   float* __restrict__ out) {
  __shared__ float4 box4[1024];
  __shared__ float area[1024];
  __shared__ u64 mask[SEGROWS * 16];
  __shared__ u64 validw[16], keepw[16];
  __shared__ short ord[K1_];
  __shared__ int ordc;

  const int b = blockIdx.x;
  const int tid = threadIdx.x;
  nms_run(sel_score + b * K1_, sel_orig + b * K1_,
          boxes + (size_t)b * N_ * 4, POST_IOU_F,
          box4, area, mask, validw, keepw);
  __syncthreads();

  if (tid == 0) {
    int cnt = 0;
    for (int p = 0; p < K1_; ++p)
      if ((keepw[p >> 6] >> (p & 63)) & 1ull) ord[cnt++] = (short)p;
    ordc = cnt;
  }
  __syncthreads();

  for (int t = tid; t < K1_ * 6; t += 1024) out[(size_t)b * K1_ * 6 + t] = 0.0f;
  __syncthreads();

  const int cnt = ordc;
  for (int q = tid; q < cnt; q += 1024) {
    int p = ord[q];
    int oi = sel_orig[b * K1_ + p];
    const float4 bp = *(const float4*)(boxes + ((size_t)b * N_ + oi) * 4);
    float* o = out + ((size_t)b * K1_ + q) * 6;
    o[0] = bp.x; o[1] = bp.y; o[2] = bp.z; o[3] = bp.w;
    o[4] = (float)sel_cls[b * K1_ + p];
    o[5] = sel_score[b * K1_ + p];
  }
}

// ---------------------------------------------------------------------------
extern "C" void kernel_launch(void* const* d_in, const int* in_sizes, int n_in,
                              void* d_out, int out_size, void* d_ws, size_t ws_size,
                              hipStream_t stream) {
  const float* cls = (const float*)d_in[0];    // (8,100000,10) f32
  const float* boxes = (const float*)d_in[1];  // (8,100000,4)  f32
  float* out = (float*)d_out;                  // (8,1000,6)    f32

  char* ws = (char*)d_ws;
  float* score1    = (float*)(ws);                     // 80000 f32
  int*   idx1      = (int*)(ws + 320000);              // 80000 i32
  int*   keep1     = (int*)(ws + 640000);              // 80000 i32
  float* sel_score = (float*)(ws + 960000);            // 8000 f32
  int*   sel_cls   = (int*)(ws + 992000);              // 8000 i32
  int*   sel_orig  = (int*)(ws + 1024000);             // 8000 i32
  u32*   cnt       = (u32*)(ws + 1056000);             // 80 u32
  u32*   flag      = (u32*)(ws + 1056320);             // 80 u32
  u64*   cand      = (u64*)(ws + 1056640);             // 80*2048 u64 = 1.31 MB

  hipLaunchKernelGGL(k_init, dim3(1), dim3(256), 0, stream, cnt, flag);
  hipLaunchKernelGGL(k_compact, dim3(2048), dim3(256), 0, stream,
                     cls, cand, cnt);
  hipLaunchKernelGGL(k_sel, dim3(B_ * C_), dim3(256), 0, stream,
                     cand, cnt, flag, score1, idx1);
  hipLaunchKernelGGL(k_topk1_fb, dim3(B_ * C_), dim3(256), 0, stream,
                     cls, flag, score1, idx1);
  hipLaunchKernelGGL(k_nms1, dim3(B_ * C_), dim3(1024), 0, stream,
                     boxes, score1, idx1, keep1);
  hipLaunchKernelGGL(k_topk2, dim3(B_), dim3(256), 0, stream,
                     score1, idx1, keep1, sel_score, sel_cls, sel_orig);
  hipLaunchKernelGGL(k_nms2_out, dim3(B_), dim3(1024), 0, stream,
                     boxes, sel_score, sel_cls, sel_orig, out);
}

// Round 4
// 1064.225 us; speedup vs baseline: 1.9668x; 1.5668x over previous
//
#include <hip/hip_runtime.h>
#include <stdint.h>

typedef unsigned int u32;
typedef unsigned long long u64;

#define B_ 8
#define N_ 100000
#define C_ 10
#define K1_ 1000
#define N2_ (C_ * K1_)
#define NBIN 4096
#define CAP 4096       // fallback / topk2 sort capacity
#define CAP_C 2048     // fast-path candidate capacity per slice
#define SEGROWS 256    // NMS mask segment rows (4 segments cover 1000)
#define MIN_CONF_F 0.05f
#define NMS_IOU_F 0.4f
#define POST_IOU_F 0.65f
#define T0_F 0.985f    // conservative fast-path threshold (count ~1500 +/- 38)

#define TOTAL_F4 (B_ * N_ * C_ / 4)  // 2,000,000 float4s
#define CBLK 512                     // compact blocks
#define LCAP 1024                    // per-block local candidate capacity

static __device__ __forceinline__ u32 next_pow2_ge(u32 x, u32 lo, u32 hi) {
  u32 n = lo;
  while (n < x && n < hi) n <<= 1;
  return n;
}

// ---------------------------------------------------------------------------
// Init: zero per-slice counters + fallback flags (ws is poisoned 0xAA).
// ---------------------------------------------------------------------------
__global__ void k_init(u32* __restrict__ cnt, u32* __restrict__ flag) {
  int t = threadIdx.x;
  if (t < B_ * C_) { cnt[t] = 0; flag[t] = 0; }
}

// ---------------------------------------------------------------------------
// Fast path pass 1 (LDS-staged): each block owns a contiguous chunk of the
// score tensor; candidates (s >= T0) append to an LDS buffer with per-slice
// local ranks; then <=80 global atomicAdds per block reserve per-slice output
// ranges; finally a scatter writes keys to cand[slice][base+rank].
// This replaces ~120k contended global atomics with ~6k.
// ---------------------------------------------------------------------------
__global__ __launch_bounds__(256) void k_compact(const float* __restrict__ cls,
                                                 u64* __restrict__ cand,
                                                 u32* __restrict__ cnt,
                                                 u32* __restrict__ flag) {
  __shared__ u32 lcnt[B_ * C_];
  __shared__ u32 sbase[B_ * C_];
  __shared__ u32 ltot;
  __shared__ u32 lovf;
  __shared__ u64 ekey[LCAP];
  __shared__ u32 emeta[LCAP];  // (slice<<16) | local_rank

  const int tid = threadIdx.x;
  if (tid < B_ * C_) lcnt[tid] = 0;
  if (tid == 0) { ltot = 0; lovf = 0; }
  __syncthreads();

  const u32 lo = (u32)blockIdx.x * ((TOTAL_F4 + CBLK - 1) / CBLK);
  u32 hi = lo + ((TOTAL_F4 + CBLK - 1) / CBLK);
  if (hi > TOTAL_F4) hi = TOTAL_F4;

  const float4* p4 = (const float4*)cls;
  for (u32 f = lo + tid; f < hi; f += 256) {
    float4 v = p4[f];
    u32 e = f * 4u;
    float vs[4] = {v.x, v.y, v.z, v.w};
#pragma unroll
    for (int j = 0; j < 4; ++j) {
      float s = vs[j];
      if (s >= T0_F) {
        u32 g = e + (u32)j;           // flat index into (B,N,C)
        u32 gi = g / (u32)C_;         // b*N + i
        u32 c = g - gi * (u32)C_;
        u32 bi = gi / (u32)N_;
        u32 i = gi - bi * (u32)N_;
        u32 slice = bi * (u32)C_ + c;
        u32 rank = atomicAdd(&lcnt[slice], 1u);
        u32 pos = atomicAdd(&ltot, 1u);
        if (pos < LCAP) {
          ekey[pos] = ((u64)__float_as_uint(s) << 32) | (u32)(~i);
          emeta[pos] = (slice << 16) | rank;
        } else {
          lovf = 1;
        }
      }
    }
  }
  __syncthreads();

  if (lovf) {
    // astronomically unlikely; force exact fallback for all slices
    if (tid < B_ * C_) flag[tid] = 1;
  }
  // reserve global ranges (true counts even on overflow, so k_sel's range
  // check and the fallback flags stay consistent)
  if (tid < B_ * C_) {
    u32 n = lcnt[tid];
    sbase[tid] = n ? atomicAdd(&cnt[tid], n) : 0u;
  }
  __syncthreads();

  u32 tot = ltot;
  if (tot > LCAP) tot = LCAP;
  for (u32 p = tid; p < tot; p += 256) {
    u32 mta = emeta[p];
    u32 slice = mta >> 16;
    u32 rank = mta & 0xFFFFu;
    u32 dst = sbase[slice] + rank;
    if (dst < CAP_C) cand[(size_t)slice * CAP_C + dst] = ekey[p];
  }
}

// ---------------------------------------------------------------------------
// Fast path pass 2: per-slice adaptive bitonic sort of candidates, emit top
// 1000 (stable: value desc, idx asc). Flags slice for fallback if count is
// out of [K1, CAP_C] or compact overflowed.
// ---------------------------------------------------------------------------
__global__ __launch_bounds__(256) void k_sel(const u64* __restrict__ cand,
                                             const u32* __restrict__ cnt,
                                             u32* __restrict__ flag,
                                             float* __restrict__ score1,
                                             int* __restrict__ idx1) {
  const int slice = blockIdx.x;
  const int tid = threadIdx.x, bd = blockDim.x;
  __shared__ u64 buf[CAP_C];

  u32 m = cnt[slice];
  if (flag[slice] || m < (u32)K1_ || m > (u32)CAP_C) {
    if (tid == 0) flag[slice] = 1;
    return;
  }
  const u32 n = next_pow2_ge(m, 1024u, (u32)CAP_C);

  for (u32 i = tid; i < n; i += bd)
    buf[i] = (i < m) ? cand[(size_t)slice * CAP_C + i] : 0ull;
  __syncthreads();

  for (u32 kk = 2; kk <= n; kk <<= 1) {
    for (u32 j = kk >> 1; j > 0; j >>= 1) {
      for (u32 i = tid; i < n; i += bd) {
        u32 l = i ^ j;
        if (l > i) {
          u64 a = buf[i], bb = buf[l];
          bool desc = ((i & kk) == 0);
          if (desc ? (a < bb) : (a > bb)) { buf[i] = bb; buf[l] = a; }
        }
      }
      __syncthreads();
    }
  }

  for (int p = tid; p < K1_; p += bd) {
    u64 e = buf[p];
    u32 k = (u32)(e >> 32);
    score1[slice * K1_ + p] = __uint_as_float(k);
    idx1[slice * K1_ + p] = (int)(~(u32)e);
  }
}

// ---------------------------------------------------------------------------
// Fallback (exact, slow) per-slice top-1000 — only runs for flagged slices.
// ---------------------------------------------------------------------------
__global__ __launch_bounds__(256) void k_topk1_fb(const float* __restrict__ cls,
                                                  const u32* __restrict__ flag,
                                                  float* __restrict__ score1,
                                                  int* __restrict__ idx1) {
  const int slice = blockIdx.x;
  if (!flag[slice]) return;
  const int b = slice / C_, c = slice % C_;
  const int tid = threadIdx.x, bd = blockDim.x;

  __shared__ u32 hist[NBIN];
  __shared__ u64 buf[CAP];
  __shared__ int sh_b1;
  __shared__ u32 sh_base, sh_T, sh_cnt;

  for (int i = tid; i < NBIN; i += bd) hist[i] = 0;
  __syncthreads();
  for (int i = tid; i < N_; i += bd) {
    float s = cls[((size_t)b * N_ + i) * C_ + c];
    if (s >= MIN_CONF_F) atomicAdd(&hist[__float_as_uint(s) >> 19], 1u);
  }
  __syncthreads();
  if (tid == 0) {
    u32 cum = 0; int b1 = -1; u32 base = 0;
    for (int bin = NBIN - 1; bin >= 0; --bin) {
      cum += hist[bin];
      if (cum >= (u32)K1_) { b1 = bin; base = cum - hist[bin]; break; }
    }
    sh_b1 = b1; sh_base = base;
    if (b1 < 0) sh_T = 0;
  }
  __syncthreads();
  const int b1 = sh_b1;

  if (b1 >= 0) {
    const u32 base = sh_base;
    for (int i = tid; i < NBIN; i += bd) hist[i] = 0;
    __syncthreads();
    for (int i = tid; i < N_; i += bd) {
      float s = cls[((size_t)b * N_ + i) * C_ + c];
      if (s >= MIN_CONF_F) {
        u32 k = __float_as_uint(s);
        if ((int)(k >> 19) == b1) atomicAdd(&hist[(k >> 7) & 0xFFFu], 1u);
      }
    }
    __syncthreads();
    if (tid == 0) {
      u32 cum = base;
      u32 T = ((u32)b1) << 19;
      for (int bin = NBIN - 1; bin >= 0; --bin) {
        cum += hist[bin];
        if (cum >= (u32)K1_) { T = (((u32)b1) << 19) | (((u32)bin) << 7); break; }
      }
      sh_T = T;
    }
    __syncthreads();
  }

  if (tid == 0) sh_cnt = 0;
  __syncthreads();
  const u32 T = sh_T;
  for (int i = tid; i < N_; i += bd) {
    float s = cls[((size_t)b * N_ + i) * C_ + c];
    if (s >= MIN_CONF_F) {
      u32 k = __float_as_uint(s);
      if (k >= T) {
        u32 pos = atomicAdd(&sh_cnt, 1u);
        if (pos < CAP) buf[pos] = ((u64)k << 32) | (u32)(~(u32)i);
      }
    }
  }
  __syncthreads();
  u32 m = sh_cnt; if (m > CAP) m = CAP;
  for (int i = tid; i < CAP; i += bd)
    if ((u32)i >= m) buf[i] = 0ull;
  __syncthreads();

  for (u32 kk = 2; kk <= CAP; kk <<= 1) {
    for (u32 j = kk >> 1; j > 0; j >>= 1) {
      for (u32 i = tid; i < CAP; i += bd) {
        u32 l = i ^ j;
        if (l > i) {
          u64 a = buf[i], bb = buf[l];
          bool desc = ((i & kk) == 0);
          if (desc ? (a < bb) : (a > bb)) { buf[i] = bb; buf[l] = a; }
        }
      }
      __syncthreads();
    }
  }

  for (int p = tid; p < K1_; p += bd) {
    u64 e = buf[p];
    u32 k = (u32)(e >> 32);
    float s; int oi;
    if (k == 0) { s = -1.0f; oi = 0; }
    else { s = __uint_as_float(k); oi = (int)(~(u32)e); }
    score1[slice * K1_ + p] = s;
    idx1[slice * K1_ + p] = oi;
  }
}

// ---------------------------------------------------------------------------
// NMS core: parallel pairwise-mask build (4 segments of 256 rows in LDS) +
// single-wave barrier-free greedy bit-scan. 1024 threads.
// ---------------------------------------------------------------------------
__device__ __forceinline__ void nms_run(const float* __restrict__ scores,
                                        const int* __restrict__ origs,
                                        const float* __restrict__ boxesB,
                                        float thr,
                                        float4* box4, float* area,
                                        u64* mask, u64* validw, u64* keepw) {
  const int tid = threadIdx.x;
  const int wave = tid >> 6, lane = tid & 63;

  {
    const int p = tid;
    float s = (p < K1_) ? scores[p] : -1.0f;
    bool v = (s >= MIN_CONF_F);
    float cx = 0.f, cy = 0.f, w = 0.f, h = 0.f;
    if (v) {
      const float4 bp = *(const float4*)(boxesB + (size_t)origs[p] * 4);
      cx = bp.x; cy = bp.y; w = bp.z; h = bp.w;
    }
    float y1 = cy - h * 0.5f, x1 = cx - w * 0.5f;
    float y2 = cy + h * 0.5f, x2 = cx + w * 0.5f;
    box4[p] = make_float4(y1, x1, y2, x2);
    area[p] = (y2 - y1) * (x2 - x1);
    u64 mb = __ballot(v);
    if (lane == 0) validw[wave] = mb;
  }
  __syncthreads();

  u64 vw = validw[tid & 15];
  u64 supp = 0;

  for (int seg = 0; seg < 4; ++seg) {
    const int ibase = seg * SEGROWS;
    const int lim = (K1_ - ibase < SEGROWS) ? (K1_ - ibase) : SEGROWS;

    for (int t = wave; t < SEGROWS * 16; t += 16) {
      const int il = t & (SEGROWS - 1);
      const int w = t >> 8;
      if (il >= lim) continue;
      const int i = ibase + il;
      u64 m = 0;
      if (w >= (i >> 6)) {
        const int j = (w << 6) | lane;
        float4 jb = box4[j];
        float ja = area[j];
        float4 ib = box4[i];
        float ia = area[i];
        float ih = fminf(ib.z, jb.z) - fmaxf(ib.x, jb.x); ih = fmaxf(ih, 0.0f);
        float iw_ = fminf(ib.w, jb.w) - fmaxf(ib.y, jb.y); iw_ = fmaxf(iw_, 0.0f);
        float inter = ih * iw_;
        float uni = (ia + ja) - inter;
        float iou = inter / fmaxf(uni, 1e-8f);
        m = __ballot((iou > thr) && (j > i));
      }
      if (lane == 0) mask[il * 16 + w] = m;
    }
    __syncthreads();

    if (tid < 64) {
      const int l = tid & 15;
      u64 r0 = mask[0 * 16 + l];
      u64 r1 = mask[1 * 16 + l];
      u64 r2 = mask[2 * 16 + l];
      u64 r3 = mask[3 * 16 + l];
      for (int il = 0; il < lim; il += 4) {
        const int i0 = ibase + il;
        const int n0 = (il + 4 < lim) ? il + 4 : il;
        const int n1 = (il + 5 < lim) ? il + 5 : il;
        const int n2 = (il + 6 < lim) ? il + 6 : il;
        const int n3 = (il + 7 < lim) ? il + 7 : il;
        u64 m0 = r0, m1 = r1, m2 = r2, m3 = r3;
        r0 = mask[n0 * 16 + l];
        r1 = mask[n1 * 16 + l];
        r2 = mask[n2 * 16 + l];
        r3 = mask[n3 * 16 + l];
        bool a;
        a = (tid == (i0 >> 6)) && (((vw & ~supp) >> (i0 & 63)) & 1ull);
        if (__any(a)) supp |= m0;
        a = (tid == ((i0 + 1) >> 6)) && (((vw & ~supp) >> ((i0 + 1) & 63)) & 1ull);
        if (__any(a)) supp |= m1;
        a = (tid == ((i0 + 2) >> 6)) && (((vw & ~supp) >> ((i0 + 2) & 63)) & 1ull);
        if (__any(a)) supp |= m2;
        a = (tid == ((i0 + 3) >> 6)) && (((vw & ~supp) >> ((i0 + 3) & 63)) & 1ull);
        if (__any(a)) supp |= m3;
      }
    }
    __syncthreads();
  }

  if (tid < 16) keepw[tid] = vw & ~supp;
}

// ---------------------------------------------------------------------------
// Kernel 2: per-(b,c) greedy NMS @ 0.4.
// ---------------------------------------------------------------------------
__global__ __launch_bounds__(1024) void k_nms1(const float* __restrict__ boxes,
                                               const float* __restrict__ score1,
                                               const int* __restrict__ idx1,
                                               int* __restrict__ keep1) {
  __shared__ float4 box4[1024];
  __shared__ float area[1024];
  __shared__ u64 mask[SEGROWS * 16];
  __shared__ u64 validw[16], keepw[16];

  const int slice = blockIdx.x;
  const int b = slice / C_;
  nms_run(score1 + slice * K1_, idx1 + slice * K1_,
          boxes + (size_t)b * N_ * 4, NMS_IOU_F,
          box4, area, mask, validw, keepw);
  __syncthreads();

  const int p = threadIdx.x;
  if (p < K1_)
    keep1[slice * K1_ + p] = (int)((keepw[p >> 6] >> (p & 63)) & 1ull);
}

// ---------------------------------------------------------------------------
// Kernel 3: per-batch top-1000 over the C*K1 survivors (stable, flat-index
// tie-break). Histogram select + adaptive bitonic.
// ---------------------------------------------------------------------------
__global__ __launch_bounds__(256) void k_topk2(const float* __restrict__ score1,
                                               const int* __restrict__ idx1,
                                               const int* __restrict__ keep1,
                                               float* __restrict__ sel_score,
                                               int* __restrict__ sel_cls,
                                               int* __restrict__ sel_orig) {
  const int b = blockIdx.x;
  const int tid = threadIdx.x, bd = blockDim.x;

  __shared__ u32 hist[NBIN];
  __shared__ u64 buf[CAP];
  __shared__ int sh_b1;
  __shared__ u32 sh_base, sh_T, sh_cnt;

  for (int i = tid; i < NBIN; i += bd) hist[i] = 0;
  __syncthreads();
  for (int f = tid; f < N2_; f += bd) {
    if (keep1[b * N2_ + f])
      atomicAdd(&hist[__float_as_uint(score1[b * N2_ + f]) >> 19], 1u);
  }
  __syncthreads();
  if (tid == 0) {
    u32 cum = 0; int b1 = -1; u32 base = 0;
    for (int bin = NBIN - 1; bin >= 0; --bin) {
      cum += hist[bin];
      if (cum >= (u32)K1_) { b1 = bin; base = cum - hist[bin]; break; }
    }
    sh_b1 = b1; sh_base = base;
    if (b1 < 0) sh_T = 0;
  }
  __syncthreads();
  const int b1 = sh_b1;

  if (b1 >= 0) {
    const u32 base = sh_base;
    for (int i = tid; i < NBIN; i += bd) hist[i] = 0;
    __syncthreads();
    for (int f = tid; f < N2_; f += bd) {
      if (keep1[b * N2_ + f]) {
        u32 k = __float_as_uint(score1[b * N2_ + f]);
        if ((int)(k >> 19) == b1) atomicAdd(&hist[(k >> 7) & 0xFFFu], 1u);
      }
    }
    __syncthreads();
    if (tid == 0) {
      u32 cum = base;
      u32 T = ((u32)b1) << 19;
      for (int bin = NBIN - 1; bin >= 0; --bin) {
        cum += hist[bin];
        if (cum >= (u32)K1_) { T = (((u32)b1) << 19) | (((u32)bin) << 7); break; }
      }
      sh_T = T;
    }
    __syncthreads();
  }

  if (tid == 0) sh_cnt = 0;
  __syncthreads();
  const u32 T = sh_T;
  for (int f = tid; f < N2_; f += bd) {
    if (keep1[b * N2_ + f]) {
      u32 k = __float_as_uint(score1[b * N2_ + f]);
      if (k >= T) {
        u32 pos = atomicAdd(&sh_cnt, 1u);
        if (pos < CAP) buf[pos] = ((u64)k << 32) | (u32)(~(u32)f);
      }
    }
  }
  __syncthreads();
  u32 m = sh_cnt; if (m > CAP) m = CAP;
  const u32 n = next_pow2_ge(m, 1024u, (u32)CAP);
  for (u32 i = tid; i < n; i += bd)
    if (i >= m) buf[i] = 0ull;
  __syncthreads();

  for (u32 kk = 2; kk <= n; kk <<= 1) {
    for (u32 j = kk >> 1; j > 0; j >>= 1) {
      for (u32 i = tid; i < n; i += bd) {
        u32 l = i ^ j;
        if (l > i) {
          u64 a = buf[i], bb = buf[l];
          bool desc = ((i & kk) == 0);
          if (desc ? (a < bb) : (a > bb)) { buf[i] = bb; buf[l] = a; }
        }
      }
      __syncthreads();
    }
  }

  for (int p = tid; p < K1_; p += bd) {
    u64 e = buf[p];
    u32 k = (u32)(e >> 32);
    float s; int cls, orig;
    if (k == 0) { s = -1.0f; cls = 0; orig = 0; }
    else {
      s = __uint_as_float(k);
      u32 f = ~(u32)e;
      cls = (int)(f / K1_);
      int slot = (int)(f - (u32)cls * K1_);
      orig = idx1[(b * C_ + cls) * K1_ + slot];
    }
    sel_score[b * K1_ + p] = s;
    sel_cls[b * K1_ + p] = cls;
    sel_orig[b * K1_ + p] = orig;
  }
}

// ---------------------------------------------------------------------------
// Kernel 4: per-batch class-agnostic NMS @ 0.65, stable compaction, output.
// ---------------------------------------------------------------------------
__global__ __launch_bounds__(1024) void k_nms2_out(const float* __restrict__ boxes,
                                                   const float* __restrict__ sel_score,
                                                   const int* __restrict__ sel_cls,
                                                   const int* __restrict__ sel_orig,
                                                   float* __restrict__ out) {
  __shared__ float4 box4[1024];
  __shared__ float area[1024];
  __shared__ u64 mask[SEGROWS * 16];
  __shared__ u64 validw[16], keepw[16];
  __shared__ short ord[K1_];
  __shared__ int ordc;

  const int b = blockIdx.x;
  const int tid = threadIdx.x;
  nms_run(sel_score + b * K1_, sel_orig + b * K1_,
          boxes + (size_t)b * N_ * 4, POST_IOU_F,
          box4, area, mask, validw, keepw);
  __syncthreads();

  if (tid == 0) {
    int cnt = 0;
    for (int p = 0; p < K1_; ++p)
      if ((keepw[p >> 6] >> (p & 63)) & 1ull) ord[cnt++] = (short)p;
    ordc = cnt;
  }
  __syncthreads();

  for (int t = tid; t < K1_ * 6; t += 1024) out[(size_t)b * K1_ * 6 + t] = 0.0f;
  __syncthreads();

  const int cnt = ordc;
  for (int q = tid; q < cnt; q += 1024) {
    int p = ord[q];
    int oi = sel_orig[b * K1_ + p];
    const float4 bp = *(const float4*)(boxes + ((size_t)b * N_ + oi) * 4);
    float* o = out + ((size_t)b * K1_ + q) * 6;
    o[0] = bp.x; o[1] = bp.y; o[2] = bp.z; o[3] = bp.w;
    o[4] = (float)sel_cls[b * K1_ + p];
    o[5] = sel_score[b * K1_ + p];
  }
}

// ---------------------------------------------------------------------------
extern "C" void kernel_launch(void* const* d_in, const int* in_sizes, int n_in,
                              void* d_out, int out_size, void* d_ws, size_t ws_size,
                              hipStream_t stream) {
  const float* cls = (const float*)d_in[0];    // (8,100000,10) f32
  const float* boxes = (const float*)d_in[1];  // (8,100000,4)  f32
  float* out = (float*)d_out;                  // (8,1000,6)    f32

  char* ws = (char*)d_ws;
  float* score1    = (float*)(ws);                     // 80000 f32
  int*   idx1      = (int*)(ws + 320000);              // 80000 i32
  int*   keep1     = (int*)(ws + 640000);              // 80000 i32
  float* sel_score = (float*)(ws + 960000);            // 8000 f32
  int*   sel_cls   = (int*)(ws + 992000);              // 8000 i32
  int*   sel_orig  = (int*)(ws + 1024000);             // 8000 i32
  u32*   cnt       = (u32*)(ws + 1056000);             // 80 u32
  u32*   flag      = (u32*)(ws + 1056320);             // 80 u32
  u64*   cand      = (u64*)(ws + 1056640);             // 80*2048 u64 = 1.31 MB

  hipLaunchKernelGGL(k_init, dim3(1), dim3(256), 0, stream, cnt, flag);
  hipLaunchKernelGGL(k_compact, dim3(CBLK), dim3(256), 0, stream,
                     cls, cand, cnt, flag);
  hipLaunchKernelGGL(k_sel, dim3(B_ * C_), dim3(256), 0, stream,
                     cand, cnt, flag, score1, idx1);
  hipLaunchKernelGGL(k_topk1_fb, dim3(B_ * C_), dim3(256), 0, stream,
                     cls, flag, score1, idx1);
  hipLaunchKernelGGL(k_nms1, dim3(B_ * C_), dim3(1024), 0, stream,
                     boxes, score1, idx1, keep1);
  hipLaunchKernelGGL(k_topk2, dim3(B_), dim3(256), 0, stream,
                     score1, idx1, keep1, sel_score, sel_cls, sel_orig);
  hipLaunchKernelGGL(k_nms2_out, dim3(B_), dim3(1024), 0, stream,
                     boxes, sel_score, sel_cls, sel_orig, out);
}

// Round 5
// 890.044 us; speedup vs baseline: 2.3517x; 1.1957x over previous
//
#include <hip/hip_runtime.h>
#include <stdint.h>

typedef unsigned int u32;
typedef unsigned long long u64;

#define B_ 8
#define N_ 100000
#define C_ 10
#define K1_ 1000
#define N2_ (C_ * K1_)
#define NBIN 4096
#define CAP 4096       // fallback / topk2 sort capacity
#define CAP_C 2048     // fast-path candidate capacity per slice
#define SEGROWS 256    // NMS mask segment rows (4 segments cover 1000)
#define MIN_CONF_F 0.05f
#define NMS_IOU_F 0.4f
#define POST_IOU_F 0.65f
#define T0_F 0.985f    // conservative fast-path threshold (count ~1500 +/- 38)

#define TOTAL_F4 (B_ * N_ * C_ / 4)  // 2,000,000 float4s
#define CBLK 512                     // compact blocks
#define LCAP 1024                    // per-block local candidate capacity

static __device__ __forceinline__ u32 next_pow2_ge(u32 x, u32 lo, u32 hi) {
  u32 n = lo;
  while (n < x && n < hi) n <<= 1;
  return n;
}

// ---------------------------------------------------------------------------
// Init: zero per-slice counters + fallback flags (ws is poisoned 0xAA).
// ---------------------------------------------------------------------------
__global__ void k_init(u32* __restrict__ cnt, u32* __restrict__ flag) {
  int t = threadIdx.x;
  if (t < B_ * C_) { cnt[t] = 0; flag[t] = 0; }
}

// ---------------------------------------------------------------------------
// Fast path pass 1 (LDS-staged compaction).
// ---------------------------------------------------------------------------
__global__ __launch_bounds__(256) void k_compact(const float* __restrict__ cls,
                                                 u64* __restrict__ cand,
                                                 u32* __restrict__ cnt,
                                                 u32* __restrict__ flag) {
  __shared__ u32 lcnt[B_ * C_];
  __shared__ u32 sbase[B_ * C_];
  __shared__ u32 ltot;
  __shared__ u32 lovf;
  __shared__ u64 ekey[LCAP];
  __shared__ u32 emeta[LCAP];  // (slice<<16) | local_rank

  const int tid = threadIdx.x;
  if (tid < B_ * C_) lcnt[tid] = 0;
  if (tid == 0) { ltot = 0; lovf = 0; }
  __syncthreads();

  const u32 lo = (u32)blockIdx.x * ((TOTAL_F4 + CBLK - 1) / CBLK);
  u32 hi = lo + ((TOTAL_F4 + CBLK - 1) / CBLK);
  if (hi > TOTAL_F4) hi = TOTAL_F4;

  const float4* p4 = (const float4*)cls;
  for (u32 f = lo + tid; f < hi; f += 256) {
    float4 v = p4[f];
    u32 e = f * 4u;
    float vs[4] = {v.x, v.y, v.z, v.w};
#pragma unroll
    for (int j = 0; j < 4; ++j) {
      float s = vs[j];
      if (s >= T0_F) {
        u32 g = e + (u32)j;           // flat index into (B,N,C)
        u32 gi = g / (u32)C_;         // b*N + i
        u32 c = g - gi * (u32)C_;
        u32 bi = gi / (u32)N_;
        u32 i = gi - bi * (u32)N_;
        u32 slice = bi * (u32)C_ + c;
        u32 rank = atomicAdd(&lcnt[slice], 1u);
        u32 pos = atomicAdd(&ltot, 1u);
        if (pos < LCAP) {
          ekey[pos] = ((u64)__float_as_uint(s) << 32) | (u32)(~i);
          emeta[pos] = (slice << 16) | rank;
        } else {
          lovf = 1;
        }
      }
    }
  }
  __syncthreads();

  if (lovf) {
    if (tid < B_ * C_) flag[tid] = 1;
  }
  if (tid < B_ * C_) {
    u32 n = lcnt[tid];
    sbase[tid] = n ? atomicAdd(&cnt[tid], n) : 0u;
  }
  __syncthreads();

  u32 tot = ltot;
  if (tot > LCAP) tot = LCAP;
  for (u32 p = tid; p < tot; p += 256) {
    u32 mta = emeta[p];
    u32 slice = mta >> 16;
    u32 rank = mta & 0xFFFFu;
    u32 dst = sbase[slice] + rank;
    if (dst < CAP_C) cand[(size_t)slice * CAP_C + dst] = ekey[p];
  }
}

// ---------------------------------------------------------------------------
// Fast path pass 2: per-slice adaptive bitonic sort, emit top 1000.
// ---------------------------------------------------------------------------
__global__ __launch_bounds__(256) void k_sel(const u64* __restrict__ cand,
                                             const u32* __restrict__ cnt,
                                             u32* __restrict__ flag,
                                             float* __restrict__ score1,
                                             int* __restrict__ idx1) {
  const int slice = blockIdx.x;
  const int tid = threadIdx.x, bd = blockDim.x;
  __shared__ u64 buf[CAP_C];

  u32 m = cnt[slice];
  if (flag[slice] || m < (u32)K1_ || m > (u32)CAP_C) {
    if (tid == 0) flag[slice] = 1;
    return;
  }
  const u32 n = next_pow2_ge(m, 1024u, (u32)CAP_C);

  for (u32 i = tid; i < n; i += bd)
    buf[i] = (i < m) ? cand[(size_t)slice * CAP_C + i] : 0ull;
  __syncthreads();

  for (u32 kk = 2; kk <= n; kk <<= 1) {
    for (u32 j = kk >> 1; j > 0; j >>= 1) {
      for (u32 i = tid; i < n; i += bd) {
        u32 l = i ^ j;
        if (l > i) {
          u64 a = buf[i], bb = buf[l];
          bool desc = ((i & kk) == 0);
          if (desc ? (a < bb) : (a > bb)) { buf[i] = bb; buf[l] = a; }
        }
      }
      __syncthreads();
    }
  }

  for (int p = tid; p < K1_; p += bd) {
    u64 e = buf[p];
    u32 k = (u32)(e >> 32);
    score1[slice * K1_ + p] = __uint_as_float(k);
    idx1[slice * K1_ + p] = (int)(~(u32)e);
  }
}

// ---------------------------------------------------------------------------
// Fallback (exact, slow) per-slice top-1000 — only runs for flagged slices.
// ---------------------------------------------------------------------------
__global__ __launch_bounds__(256) void k_topk1_fb(const float* __restrict__ cls,
                                                  const u32* __restrict__ flag,
                                                  float* __restrict__ score1,
                                                  int* __restrict__ idx1) {
  const int slice = blockIdx.x;
  if (!flag[slice]) return;
  const int b = slice / C_, c = slice % C_;
  const int tid = threadIdx.x, bd = blockDim.x;

  __shared__ u32 hist[NBIN];
  __shared__ u64 buf[CAP];
  __shared__ int sh_b1;
  __shared__ u32 sh_base, sh_T, sh_cnt;

  for (int i = tid; i < NBIN; i += bd) hist[i] = 0;
  __syncthreads();
  for (int i = tid; i < N_; i += bd) {
    float s = cls[((size_t)b * N_ + i) * C_ + c];
    if (s >= MIN_CONF_F) atomicAdd(&hist[__float_as_uint(s) >> 19], 1u);
  }
  __syncthreads();
  if (tid == 0) {
    u32 cum = 0; int b1 = -1; u32 base = 0;
    for (int bin = NBIN - 1; bin >= 0; --bin) {
      cum += hist[bin];
      if (cum >= (u32)K1_) { b1 = bin; base = cum - hist[bin]; break; }
    }
    sh_b1 = b1; sh_base = base;
    if (b1 < 0) sh_T = 0;
  }
  __syncthreads();
  const int b1 = sh_b1;

  if (b1 >= 0) {
    const u32 base = sh_base;
    for (int i = tid; i < NBIN; i += bd) hist[i] = 0;
    __syncthreads();
    for (int i = tid; i < N_; i += bd) {
      float s = cls[((size_t)b * N_ + i) * C_ + c];
      if (s >= MIN_CONF_F) {
        u32 k = __float_as_uint(s);
        if ((int)(k >> 19) == b1) atomicAdd(&hist[(k >> 7) & 0xFFFu], 1u);
      }
    }
    __syncthreads();
    if (tid == 0) {
      u32 cum = base;
      u32 T = ((u32)b1) << 19;
      for (int bin = NBIN - 1; bin >= 0; --bin) {
        cum += hist[bin];
        if (cum >= (u32)K1_) { T = (((u32)b1) << 19) | (((u32)bin) << 7); break; }
      }
      sh_T = T;
    }
    __syncthreads();
  }

  if (tid == 0) sh_cnt = 0;
  __syncthreads();
  const u32 T = sh_T;
  for (int i = tid; i < N_; i += bd) {
    float s = cls[((size_t)b * N_ + i) * C_ + c];
    if (s >= MIN_CONF_F) {
      u32 k = __float_as_uint(s);
      if (k >= T) {
        u32 pos = atomicAdd(&sh_cnt, 1u);
        if (pos < CAP) buf[pos] = ((u64)k << 32) | (u32)(~(u32)i);
      }
    }
  }
  __syncthreads();
  u32 m = sh_cnt; if (m > CAP) m = CAP;
  for (int i = tid; i < CAP; i += bd)
    if ((u32)i >= m) buf[i] = 0ull;
  __syncthreads();

  for (u32 kk = 2; kk <= CAP; kk <<= 1) {
    for (u32 j = kk >> 1; j > 0; j >>= 1) {
      for (u32 i = tid; i < CAP; i += bd) {
        u32 l = i ^ j;
        if (l > i) {
          u64 a = buf[i], bb = buf[l];
          bool desc = ((i & kk) == 0);
          if (desc ? (a < bb) : (a > bb)) { buf[i] = bb; buf[l] = a; }
        }
      }
      __syncthreads();
    }
  }

  for (int p = tid; p < K1_; p += bd) {
    u64 e = buf[p];
    u32 k = (u32)(e >> 32);
    float s; int oi;
    if (k == 0) { s = -1.0f; oi = 0; }
    else { s = __uint_as_float(k); oi = (int)(~(u32)e); }
    score1[slice * K1_ + p] = s;
    idx1[slice * K1_ + p] = oi;
  }
}

// ---------------------------------------------------------------------------
// NMS core v2: register-cached column build + single-wave greedy bit-scan.
// Each wave owns one 64-wide mask word (j = word*64+lane held in registers);
// per row only box4[i]/area[i] are broadcast-read from LDS. The IoU>thr test
// uses an exact division-free form: RN(inter/den) > c  <=>  inter >(=) M*den
// in double, M = (c + nextafter(c))/2 (exact; M*den exact at 49 bits), with
// the tie (inter/den == M exactly) direction set by mantissa evenness of c.
// ---------------------------------------------------------------------------
__device__ __forceinline__ void nms_run(const float* __restrict__ scores,
                                        const int* __restrict__ origs,
                                        const float* __restrict__ boxesB,
                                        float thr,
                                        float4* box4, float* area,
                                        u64* mask, u64* validw, u64* keepw) {
  const int tid = threadIdx.x;
  const int wave = tid >> 6, lane = tid & 63;

  // ---- load boxes -> corners + areas; valid bitmask ----
  {
    const int p = tid;
    float s = (p < K1_) ? scores[p] : -1.0f;
    bool v = (s >= MIN_CONF_F);
    float cx = 0.f, cy = 0.f, w = 0.f, h = 0.f;
    if (v) {
      const float4 bp = *(const float4*)(boxesB + (size_t)origs[p] * 4);
      cx = bp.x; cy = bp.y; w = bp.z; h = bp.w;
    }
    float y1 = cy - h * 0.5f, x1 = cx - w * 0.5f;
    float y2 = cy + h * 0.5f, x2 = cx + w * 0.5f;
    box4[p] = make_float4(y1, x1, y2, x2);
    area[p] = (y2 - y1) * (x2 - x1);
    u64 mb = __ballot(v);
    if (lane == 0) validw[wave] = mb;
  }
  __syncthreads();

  // ---- exact threshold constants ----
  const float cf = thr;
  const float cnext = __uint_as_float(__float_as_uint(cf) + 1u);
  const double M = ((double)cf + (double)cnext) * 0.5;
  const bool strict = ((__float_as_uint(cf) & 1u) == 0u);  // c even -> RN(mid)=c -> strict >

  // ---- wave -> word mapping, balanced per SIMD quartet {s,7-s,8+s,15-s} ----
  const int ss = wave & 3, qq = wave >> 2;
  int word;
  if (qq == 0) word = ss;
  else if (qq == 1) word = 7 - ss;
  else if (qq == 2) word = 8 + ss;
  else word = 15 - ss;

  const int j = (word << 6) | lane;
  const float4 jb = box4[j];
  const float ja = area[j];

  u64 vw = validw[tid & 15];
  u64 supp = 0;

  for (int seg = 0; seg < 4; ++seg) {
    const int ibase = seg * SEGROWS;
    const int lim = (K1_ - ibase < SEGROWS) ? (K1_ - ibase) : SEGROWS;
    // rows with i >= 64*(word+1) have no j>i in this word -> zero
    int cend = ((word + 1) << 6) - ibase;
    if (cend < 0) cend = 0;
    if (cend > lim) cend = lim;

    for (int il = 0; il < cend; ++il) {
      const int i = ibase + il;
      const float4 ib = box4[i];   // broadcast (same addr all lanes)
      const float ia = area[i];
      float ih = fminf(ib.z, jb.z) - fmaxf(ib.x, jb.x); ih = fmaxf(ih, 0.0f);
      float iw_ = fminf(ib.w, jb.w) - fmaxf(ib.y, jb.y); iw_ = fmaxf(iw_, 0.0f);
      float inter = ih * iw_;
      float uni = (ia + ja) - inter;
      float den = fmaxf(uni, 1e-8f);
      double lhs = (double)inter;
      double rhs = M * (double)den;
      bool iouc = strict ? (lhs > rhs) : (lhs >= rhs);
      u64 m = __ballot(iouc && (j > i));
      if (lane == 0) mask[il * 16 + word] = m;
    }
    for (int il = cend; il < lim; ++il)
      if (lane == 0) mask[il * 16 + word] = 0;
    __syncthreads();

    // ---- serial greedy scan over this segment: wave 0 only, no barriers ----
    if (tid < 64) {
      const int l = tid & 15;
      u64 r0 = mask[0 * 16 + l];
      u64 r1 = mask[1 * 16 + l];
      u64 r2 = mask[2 * 16 + l];
      u64 r3 = mask[3 * 16 + l];
      for (int il = 0; il < lim; il += 4) {
        const int i0 = ibase + il;
        const int n0 = (il + 4 < lim) ? il + 4 : il;
        const int n1 = (il + 5 < lim) ? il + 5 : il;
        const int n2 = (il + 6 < lim) ? il + 6 : il;
        const int n3 = (il + 7 < lim) ? il + 7 : il;
        u64 m0 = r0, m1 = r1, m2 = r2, m3 = r3;
        r0 = mask[n0 * 16 + l];
        r1 = mask[n1 * 16 + l];
        r2 = mask[n2 * 16 + l];
        r3 = mask[n3 * 16 + l];
        bool a;
        a = (tid == (i0 >> 6)) && (((vw & ~supp) >> (i0 & 63)) & 1ull);
        if (__any(a)) supp |= m0;
        a = (tid == ((i0 + 1) >> 6)) && (((vw & ~supp) >> ((i0 + 1) & 63)) & 1ull);
        if (__any(a)) supp |= m1;
        a = (tid == ((i0 + 2) >> 6)) && (((vw & ~supp) >> ((i0 + 2) & 63)) & 1ull);
        if (__any(a)) supp |= m2;
        a = (tid == ((i0 + 3) >> 6)) && (((vw & ~supp) >> ((i0 + 3) & 63)) & 1ull);
        if (__any(a)) supp |= m3;
      }
    }
    __syncthreads();
  }

  if (tid < 16) keepw[tid] = vw & ~supp;
}

// ---------------------------------------------------------------------------
// Kernel 2: per-(b,c) greedy NMS @ 0.4.
// ---------------------------------------------------------------------------
__global__ __launch_bounds__(1024) void k_nms1(const float* __restrict__ boxes,
                                               const float* __restrict__ score1,
                                               const int* __restrict__ idx1,
                                               int* __restrict__ keep1) {
  __shared__ float4 box4[1024];
  __shared__ float area[1024];
  __shared__ u64 mask[SEGROWS * 16];
  __shared__ u64 validw[16], keepw[16];

  const int slice = blockIdx.x;
  const int b = slice / C_;
  nms_run(score1 + slice * K1_, idx1 + slice * K1_,
          boxes + (size_t)b * N_ * 4, NMS_IOU_F,
          box4, area, mask, validw, keepw);
  __syncthreads();

  const int p = threadIdx.x;
  if (p < K1_)
    keep1[slice * K1_ + p] = (int)((keepw[p >> 6] >> (p & 63)) & 1ull);
}

// ---------------------------------------------------------------------------
// Kernel 3: per-batch top-1000 over the C*K1 survivors (stable, flat-index
// tie-break). Histogram select + adaptive bitonic.
// ---------------------------------------------------------------------------
__global__ __launch_bounds__(256) void k_topk2(const float* __restrict__ score1,
                                               const int* __restrict__ idx1,
                                               const int* __restrict__ keep1,
                                               float* __restrict__ sel_score,
                                               int* __restrict__ sel_cls,
                                               int* __restrict__ sel_orig) {
  const int b = blockIdx.x;
  const int tid = threadIdx.x, bd = blockDim.x;

  __shared__ u32 hist[NBIN];
  __shared__ u64 buf[CAP];
  __shared__ int sh_b1;
  __shared__ u32 sh_base, sh_T, sh_cnt;

  for (int i = tid; i < NBIN; i += bd) hist[i] = 0;
  __syncthreads();
  for (int f = tid; f < N2_; f += bd) {
    if (keep1[b * N2_ + f])
      atomicAdd(&hist[__float_as_uint(score1[b * N2_ + f]) >> 19], 1u);
  }
  __syncthreads();
  if (tid == 0) {
    u32 cum = 0; int b1 = -1; u32 base = 0;
    for (int bin = NBIN - 1; bin >= 0; --bin) {
      cum += hist[bin];
      if (cum >= (u32)K1_) { b1 = bin; base = cum - hist[bin]; break; }
    }
    sh_b1 = b1; sh_base = base;
    if (b1 < 0) sh_T = 0;
  }
  __syncthreads();
  const int b1 = sh_b1;

  if (b1 >= 0) {
    const u32 base = sh_base;
    for (int i = tid; i < NBIN; i += bd) hist[i] = 0;
    __syncthreads();
    for (int f = tid; f < N2_; f += bd) {
      if (keep1[b * N2_ + f]) {
        u32 k = __float_as_uint(score1[b * N2_ + f]);
        if ((int)(k >> 19) == b1) atomicAdd(&hist[(k >> 7) & 0xFFFu], 1u);
      }
    }
    __syncthreads();
    if (tid == 0) {
      u32 cum = base;
      u32 T = ((u32)b1) << 19;
      for (int bin = NBIN - 1; bin >= 0; --bin) {
        cum += hist[bin];
        if (cum >= (u32)K1_) { T = (((u32)b1) << 19) | (((u32)bin) << 7); break; }
      }
      sh_T = T;
    }
    __syncthreads();
  }

  if (tid == 0) sh_cnt = 0;
  __syncthreads();
  const u32 T = sh_T;
  for (int f = tid; f < N2_; f += bd) {
    if (keep1[b * N2_ + f]) {
      u32 k = __float_as_uint(score1[b * N2_ + f]);
      if (k >= T) {
        u32 pos = atomicAdd(&sh_cnt, 1u);
        if (pos < CAP) buf[pos] = ((u64)k << 32) | (u32)(~(u32)f);
      }
    }
  }
  __syncthreads();
  u32 m = sh_cnt; if (m > CAP) m = CAP;
  const u32 n = next_pow2_ge(m, 1024u, (u32)CAP);
  for (u32 i = tid; i < n; i += bd)
    if (i >= m) buf[i] = 0ull;
  __syncthreads();

  for (u32 kk = 2; kk <= n; kk <<= 1) {
    for (u32 j = kk >> 1; j > 0; j >>= 1) {
      for (u32 i = tid; i < n; i += bd) {
        u32 l = i ^ j;
        if (l > i) {
          u64 a = buf[i], bb = buf[l];
          bool desc = ((i & kk) == 0);
          if (desc ? (a < bb) : (a > bb)) { buf[i] = bb; buf[l] = a; }
        }
      }
      __syncthreads();
    }
  }

  for (int p = tid; p < K1_; p += bd) {
    u64 e = buf[p];
    u32 k = (u32)(e >> 32);
    float s; int cls, orig;
    if (k == 0) { s = -1.0f; cls = 0; orig = 0; }
    else {
      s = __uint_as_float(k);
      u32 f = ~(u32)e;
      cls = (int)(f / K1_);
      int slot = (int)(f - (u32)cls * K1_);
      orig = idx1[(b * C_ + cls) * K1_ + slot];
    }
    sel_score[b * K1_ + p] = s;
    sel_cls[b * K1_ + p] = cls;
    sel_orig[b * K1_ + p] = orig;
  }
}

// ---------------------------------------------------------------------------
// Kernel 4: per-batch class-agnostic NMS @ 0.65, stable compaction, output.
// ---------------------------------------------------------------------------
__global__ __launch_bounds__(1024) void k_nms2_out(const float* __restrict__ boxes,
                                                   const float* __restrict__ sel_score,
                                                   const int* __restrict__ sel_cls,
                                                   const int* __restrict__ sel_orig,
                                                   float* __restrict__ out) {
  __shared__ float4 box4[1024];
  __shared__ float area[1024];
  __shared__ u64 mask[SEGROWS * 16];
  __shared__ u64 validw[16], keepw[16];
  __shared__ short ord[K1_];
  __shared__ int ordc;

  const int b = blockIdx.x;
  const int tid = threadIdx.x;
  nms_run(sel_score + b * K1_, sel_orig + b * K1_,
          boxes + (size_t)b * N_ * 4, POST_IOU_F,
          box4, area, mask, validw, keepw);
  __syncthreads();

  if (tid == 0) {
    int cnt = 0;
    for (int p = 0; p < K1_; ++p)
      if ((keepw[p >> 6] >> (p & 63)) & 1ull) ord[cnt++] = (short)p;
    ordc = cnt;
  }
  __syncthreads();

  for (int t = tid; t < K1_ * 6; t += 1024) out[(size_t)b * K1_ * 6 + t] = 0.0f;
  __syncthreads();

  const int cnt = ordc;
  for (int q = tid; q < cnt; q += 1024) {
    int p = ord[q];
    int oi = sel_orig[b * K1_ + p];
    const float4 bp = *(const float4*)(boxes + ((size_t)b * N_ + oi) * 4);
    float* o = out + ((size_t)b * K1_ + q) * 6;
    o[0] = bp.x; o[1] = bp.y; o[2] = bp.z; o[3] = bp.w;
    o[4] = (float)sel_cls[b * K1_ + p];
    o[5] = sel_score[b * K1_ + p];
  }
}

// ---------------------------------------------------------------------------
extern "C" void kernel_launch(void* const* d_in, const int* in_sizes, int n_in,
                              void* d_out, int out_size, void* d_ws, size_t ws_size,
                              hipStream_t stream) {
  const float* cls = (const float*)d_in[0];    // (8,100000,10) f32
  const float* boxes = (const float*)d_in[1];  // (8,100000,4)  f32
  float* out = (float*)d_out;                  // (8,1000,6)    f32

  char* ws = (char*)d_ws;
  float* score1    = (float*)(ws);                     // 80000 f32
  int*   idx1      = (int*)(ws + 320000);              // 80000 i32
  int*   keep1     = (int*)(ws + 640000);              // 80000 i32
  float* sel_score = (float*)(ws + 960000);            // 8000 f32
  int*   sel_cls   = (int*)(ws + 992000);              // 8000 i32
  int*   sel_orig  = (int*)(ws + 1024000);             // 8000 i32
  u32*   cnt       = (u32*)(ws + 1056000);             // 80 u32
  u32*   flag      = (u32*)(ws + 1056320);             // 80 u32
  u64*   cand      = (u64*)(ws + 1056640);             // 80*2048 u64 = 1.31 MB

  hipLaunchKernelGGL(k_init, dim3(1), dim3(256), 0, stream, cnt, flag);
  hipLaunchKernelGGL(k_compact, dim3(CBLK), dim3(256), 0, stream,
                     cls, cand, cnt, flag);
  hipLaunchKernelGGL(k_sel, dim3(B_ * C_), dim3(256), 0, stream,
                     cand, cnt, flag, score1, idx1);
  hipLaunchKernelGGL(k_topk1_fb, dim3(B_ * C_), dim3(256), 0, stream,
                     cls, flag, score1, idx1);
  hipLaunchKernelGGL(k_nms1, dim3(B_ * C_), dim3(1024), 0, stream,
                     boxes, score1, idx1, keep1);
  hipLaunchKernelGGL(k_topk2, dim3(B_), dim3(256), 0, stream,
                     score1, idx1, keep1, sel_score, sel_cls, sel_orig);
  hipLaunchKernelGGL(k_nms2_out, dim3(B_), dim3(1024), 0, stream,
                     boxes, sel_score, sel_cls, sel_orig, out);
}

// Round 6
// 700.055 us; speedup vs baseline: 2.9899x; 1.2714x over previous
//
#include <hip/hip_runtime.h>
#include <stdint.h>

typedef unsigned int u32;
typedef unsigned long long u64;

#define B_ 8
#define N_ 100000
#define C_ 10
#define K1_ 1000
#define N2_ (C_ * K1_)
#define NBIN 4096
#define CAP 4096       // fallback / topk2 sort capacity
#define CAP_C 2048     // fast-path candidate capacity per slice
#define SEGROWS 256    // NMS mask segment rows (4 segments cover 1000)
#define MIN_CONF_F 0.05f
#define NMS_IOU_F 0.4f
#define POST_IOU_F 0.65f
#define T0_F 0.985f    // conservative fast-path threshold (count ~1500 +/- 38)

#define TOTAL_F4 (B_ * N_ * C_ / 4)  // 2,000,000 float4s
#define CBLK 512                     // compact blocks
#define LCAP 1024                    // per-block local candidate capacity

static __device__ __forceinline__ u32 next_pow2_ge(u32 x, u32 lo, u32 hi) {
  u32 n = lo;
  while (n < x && n < hi) n <<= 1;
  return n;
}

// ---------------------------------------------------------------------------
// Init: zero per-slice counters + fallback flags (ws is poisoned 0xAA).
// ---------------------------------------------------------------------------
__global__ void k_init(u32* __restrict__ cnt, u32* __restrict__ flag) {
  int t = threadIdx.x;
  if (t < B_ * C_) { cnt[t] = 0; flag[t] = 0; }
}

// ---------------------------------------------------------------------------
// Fast path pass 1 (LDS-staged compaction).
// ---------------------------------------------------------------------------
__global__ __launch_bounds__(256) void k_compact(const float* __restrict__ cls,
                                                 u64* __restrict__ cand,
                                                 u32* __restrict__ cnt,
                                                 u32* __restrict__ flag) {
  __shared__ u32 lcnt[B_ * C_];
  __shared__ u32 sbase[B_ * C_];
  __shared__ u32 ltot;
  __shared__ u32 lovf;
  __shared__ u64 ekey[LCAP];
  __shared__ u32 emeta[LCAP];  // (slice<<16) | local_rank

  const int tid = threadIdx.x;
  if (tid < B_ * C_) lcnt[tid] = 0;
  if (tid == 0) { ltot = 0; lovf = 0; }
  __syncthreads();

  const u32 lo = (u32)blockIdx.x * ((TOTAL_F4 + CBLK - 1) / CBLK);
  u32 hi = lo + ((TOTAL_F4 + CBLK - 1) / CBLK);
  if (hi > TOTAL_F4) hi = TOTAL_F4;

  const float4* p4 = (const float4*)cls;
  for (u32 f = lo + tid; f < hi; f += 256) {
    float4 v = p4[f];
    u32 e = f * 4u;
    float vs[4] = {v.x, v.y, v.z, v.w};
#pragma unroll
    for (int j = 0; j < 4; ++j) {
      float s = vs[j];
      if (s >= T0_F) {
        u32 g = e + (u32)j;           // flat index into (B,N,C)
        u32 gi = g / (u32)C_;         // b*N + i
        u32 c = g - gi * (u32)C_;
        u32 bi = gi / (u32)N_;
        u32 i = gi - bi * (u32)N_;
        u32 slice = bi * (u32)C_ + c;
        u32 rank = atomicAdd(&lcnt[slice], 1u);
        u32 pos = atomicAdd(&ltot, 1u);
        if (pos < LCAP) {
          ekey[pos] = ((u64)__float_as_uint(s) << 32) | (u32)(~i);
          emeta[pos] = (slice << 16) | rank;
        } else {
          lovf = 1;
        }
      }
    }
  }
  __syncthreads();

  if (lovf) {
    if (tid < B_ * C_) flag[tid] = 1;
  }
  if (tid < B_ * C_) {
    u32 n = lcnt[tid];
    sbase[tid] = n ? atomicAdd(&cnt[tid], n) : 0u;
  }
  __syncthreads();

  u32 tot = ltot;
  if (tot > LCAP) tot = LCAP;
  for (u32 p = tid; p < tot; p += 256) {
    u32 mta = emeta[p];
    u32 slice = mta >> 16;
    u32 rank = mta & 0xFFFFu;
    u32 dst = sbase[slice] + rank;
    if (dst < CAP_C) cand[(size_t)slice * CAP_C + dst] = ekey[p];
  }
}

// ---------------------------------------------------------------------------
// Fast path pass 2: per-slice adaptive bitonic sort, emit top 1000.
// ---------------------------------------------------------------------------
__global__ __launch_bounds__(256) void k_sel(const u64* __restrict__ cand,
                                             const u32* __restrict__ cnt,
                                             u32* __restrict__ flag,
                                             float* __restrict__ score1,
                                             int* __restrict__ idx1) {
  const int slice = blockIdx.x;
  const int tid = threadIdx.x, bd = blockDim.x;
  __shared__ u64 buf[CAP_C];

  u32 m = cnt[slice];
  if (flag[slice] || m < (u32)K1_ || m > (u32)CAP_C) {
    if (tid == 0) flag[slice] = 1;
    return;
  }
  const u32 n = next_pow2_ge(m, 1024u, (u32)CAP_C);

  for (u32 i = tid; i < n; i += bd)
    buf[i] = (i < m) ? cand[(size_t)slice * CAP_C + i] : 0ull;
  __syncthreads();

  for (u32 kk = 2; kk <= n; kk <<= 1) {
    for (u32 j = kk >> 1; j > 0; j >>= 1) {
      for (u32 i = tid; i < n; i += bd) {
        u32 l = i ^ j;
        if (l > i) {
          u64 a = buf[i], bb = buf[l];
          bool desc = ((i & kk) == 0);
          if (desc ? (a < bb) : (a > bb)) { buf[i] = bb; buf[l] = a; }
        }
      }
      __syncthreads();
    }
  }

  for (int p = tid; p < K1_; p += bd) {
    u64 e = buf[p];
    u32 k = (u32)(e >> 32);
    score1[slice * K1_ + p] = __uint_as_float(k);
    idx1[slice * K1_ + p] = (int)(~(u32)e);
  }
}

// ---------------------------------------------------------------------------
// Fallback (exact, slow) per-slice top-1000 — only runs for flagged slices.
// ---------------------------------------------------------------------------
__global__ __launch_bounds__(256) void k_topk1_fb(const float* __restrict__ cls,
                                                  const u32* __restrict__ flag,
                                                  float* __restrict__ score1,
                                                  int* __restrict__ idx1) {
  const int slice = blockIdx.x;
  if (!flag[slice]) return;
  const int b = slice / C_, c = slice % C_;
  const int tid = threadIdx.x, bd = blockDim.x;

  __shared__ u32 hist[NBIN];
  __shared__ u64 buf[CAP];
  __shared__ int sh_b1;
  __shared__ u32 sh_base, sh_T, sh_cnt;

  for (int i = tid; i < NBIN; i += bd) hist[i] = 0;
  __syncthreads();
  for (int i = tid; i < N_; i += bd) {
    float s = cls[((size_t)b * N_ + i) * C_ + c];
    if (s >= MIN_CONF_F) atomicAdd(&hist[__float_as_uint(s) >> 19], 1u);
  }
  __syncthreads();
  if (tid == 0) {
    u32 cum = 0; int b1 = -1; u32 base = 0;
    for (int bin = NBIN - 1; bin >= 0; --bin) {
      cum += hist[bin];
      if (cum >= (u32)K1_) { b1 = bin; base = cum - hist[bin]; break; }
    }
    sh_b1 = b1; sh_base = base;
    if (b1 < 0) sh_T = 0;
  }
  __syncthreads();
  const int b1 = sh_b1;

  if (b1 >= 0) {
    const u32 base = sh_base;
    for (int i = tid; i < NBIN; i += bd) hist[i] = 0;
    __syncthreads();
    for (int i = tid; i < N_; i += bd) {
      float s = cls[((size_t)b * N_ + i) * C_ + c];
      if (s >= MIN_CONF_F) {
        u32 k = __float_as_uint(s);
        if ((int)(k >> 19) == b1) atomicAdd(&hist[(k >> 7) & 0xFFFu], 1u);
      }
    }
    __syncthreads();
    if (tid == 0) {
      u32 cum = base;
      u32 T = ((u32)b1) << 19;
      for (int bin = NBIN - 1; bin >= 0; --bin) {
        cum += hist[bin];
        if (cum >= (u32)K1_) { T = (((u32)b1) << 19) | (((u32)bin) << 7); break; }
      }
      sh_T = T;
    }
    __syncthreads();
  }

  if (tid == 0) sh_cnt = 0;
  __syncthreads();
  const u32 T = sh_T;
  for (int i = tid; i < N_; i += bd) {
    float s = cls[((size_t)b * N_ + i) * C_ + c];
    if (s >= MIN_CONF_F) {
      u32 k = __float_as_uint(s);
      if (k >= T) {
        u32 pos = atomicAdd(&sh_cnt, 1u);
        if (pos < CAP) buf[pos] = ((u64)k << 32) | (u32)(~(u32)i);
      }
    }
  }
  __syncthreads();
  u32 m = sh_cnt; if (m > CAP) m = CAP;
  for (int i = tid; i < CAP; i += bd)
    if ((u32)i >= m) buf[i] = 0ull;
  __syncthreads();

  for (u32 kk = 2; kk <= CAP; kk <<= 1) {
    for (u32 j = kk >> 1; j > 0; j >>= 1) {
      for (u32 i = tid; i < CAP; i += bd) {
        u32 l = i ^ j;
        if (l > i) {
          u64 a = buf[i], bb = buf[l];
          bool desc = ((i & kk) == 0);
          if (desc ? (a < bb) : (a > bb)) { buf[i] = bb; buf[l] = a; }
        }
      }
      __syncthreads();
    }
  }

  for (int p = tid; p < K1_; p += bd) {
    u64 e = buf[p];
    u32 k = (u32)(e >> 32);
    float s; int oi;
    if (k == 0) { s = -1.0f; oi = 0; }
    else { s = __uint_as_float(k); oi = (int)(~(u32)e); }
    score1[slice * K1_ + p] = s;
    idx1[slice * K1_ + p] = oi;
  }
}

// ---------------------------------------------------------------------------
// NMS core v3: lane-per-row tiled build (latency-free j-loop, boxes in regs,
// broadcast LDS reads, 1-op/j bit accumulate) + single-wave greedy bit-scan.
// Mask layout: row-major mask[il][16] with XOR column swizzle
// (col' = w ^ (il&15)) so the scan's 16-lane reads are conflict-free.
// IoU>thr uses the exact division-free f64 midpoint test (validated R5).
// ---------------------------------------------------------------------------
__device__ __forceinline__ void nms_run(const float* __restrict__ scores,
                                        const int* __restrict__ origs,
                                        const float* __restrict__ boxesB,
                                        float thr,
                                        float4* box4, float* area,
                                        u64* mask, u64* validw, u64* keepw) {
  const int tid = threadIdx.x;
  const int wave = tid >> 6, lane = tid & 63;

  // ---- load boxes -> corners + areas; valid bitmask ----
  {
    const int p = tid;
    float s = (p < K1_) ? scores[p] : -1.0f;
    bool v = (s >= MIN_CONF_F);
    float cx = 0.f, cy = 0.f, w = 0.f, h = 0.f;
    if (v) {
      const float4 bp = *(const float4*)(boxesB + (size_t)origs[p] * 4);
      cx = bp.x; cy = bp.y; w = bp.z; h = bp.w;
    }
    float y1 = cy - h * 0.5f, x1 = cx - w * 0.5f;
    float y2 = cy + h * 0.5f, x2 = cx + w * 0.5f;
    box4[p] = make_float4(y1, x1, y2, x2);
    area[p] = (y2 - y1) * (x2 - x1);
    u64 mb = __ballot(v);
    if (lane == 0) validw[wave] = mb;
  }
  __syncthreads();

  // ---- exact threshold constants ----
  const float cf = thr;
  const float cnext = __uint_as_float(__float_as_uint(cf) + 1u);
  const double M = ((double)cf + (double)cnext) * 0.5;
  const bool strict = ((__float_as_uint(cf) & 1u) == 0u);

  u64 vw = validw[tid & 15];
  u64 supp = 0;

  for (int seg = 0; seg < 4; ++seg) {
    const int ibase = seg * SEGROWS;
    const int lim = (K1_ - ibase < SEGROWS) ? (K1_ - ibase) : SEGROWS;

    // ---- build: 64 tile-slots (rtl 0..3 x w 0..15), 4 per wave ----
    for (int t = wave; t < 64; t += 16) {
      const int rtl = t >> 4;            // row-tile within segment
      const int w = t & 15;              // column word
      const int il = (rtl << 6) | lane;  // row within segment (lane = row)
      const int i = ibase + il;          // global row (< 1024)
      const int rtg = (ibase >> 6) + rtl;
      u64 m = 0;
      if (w >= rtg) {
        const float4 ib = box4[i];       // per-lane register copy
        const float ia = area[i];
        const float4* jcol = &box4[w << 6];
        const float* jare = &area[w << 6];
        u32 mhi = 0, mlo = 0;
#pragma unroll 8
        for (int j = 63; j >= 32; --j) {
          float4 jb = jcol[j];           // broadcast LDS read
          float ja = jare[j];
          float ih = fminf(ib.z, jb.z) - fmaxf(ib.x, jb.x); ih = fmaxf(ih, 0.0f);
          float iw_ = fminf(ib.w, jb.w) - fmaxf(ib.y, jb.y); iw_ = fmaxf(iw_, 0.0f);
          float inter = ih * iw_;
          float den = fmaxf((ia + ja) - inter, 1e-8f);
          bool p_ = strict ? ((double)inter > M * (double)den)
                           : ((double)inter >= M * (double)den);
          mhi = (mhi << 1) | (p_ ? 1u : 0u);
        }
#pragma unroll 8
        for (int j = 31; j >= 0; --j) {
          float4 jb = jcol[j];
          float ja = jare[j];
          float ih = fminf(ib.z, jb.z) - fmaxf(ib.x, jb.x); ih = fmaxf(ih, 0.0f);
          float iw_ = fminf(ib.w, jb.w) - fmaxf(ib.y, jb.y); iw_ = fmaxf(iw_, 0.0f);
          float inter = ih * iw_;
          float den = fmaxf((ia + ja) - inter, 1e-8f);
          bool p_ = strict ? ((double)inter > M * (double)den)
                           : ((double)inter >= M * (double)den);
          mlo = (mlo << 1) | (p_ ? 1u : 0u);
        }
        m = ((u64)mhi << 32) | (u64)mlo;
        if (w == rtg)  // diagonal tile: keep only bits j_global > i (bit > lane)
          m &= (lane == 63) ? 0ull : (~0ull << (lane + 1));
      }
      mask[il * 16 + (w ^ (il & 15))] = m;
    }
    __syncthreads();

    // ---- serial greedy scan over this segment: wave 0 only, no barriers ----
    if (tid < 64) {
      const int l = tid & 15;
      u64 r0 = mask[0 * 16 + (l ^ 0)];
      u64 r1 = mask[1 * 16 + (l ^ 1)];
      u64 r2 = mask[2 * 16 + (l ^ 2)];
      u64 r3 = mask[3 * 16 + (l ^ 3)];
      for (int il = 0; il < lim; il += 4) {
        const int i0 = ibase + il;
        const int n0 = (il + 4 < lim) ? il + 4 : il;
        const int n1 = (il + 5 < lim) ? il + 5 : il;
        const int n2 = (il + 6 < lim) ? il + 6 : il;
        const int n3 = (il + 7 < lim) ? il + 7 : il;
        u64 m0 = r0, m1 = r1, m2 = r2, m3 = r3;
        r0 = mask[n0 * 16 + (l ^ (n0 & 15))];
        r1 = mask[n1 * 16 + (l ^ (n1 & 15))];
        r2 = mask[n2 * 16 + (l ^ (n2 & 15))];
        r3 = mask[n3 * 16 + (l ^ (n3 & 15))];
        bool a;
        a = (tid == (i0 >> 6)) && (((vw & ~supp) >> (i0 & 63)) & 1ull);
        if (__any(a)) supp |= m0;
        a = (tid == ((i0 + 1) >> 6)) && (((vw & ~supp) >> ((i0 + 1) & 63)) & 1ull);
        if (__any(a)) supp |= m1;
        a = (tid == ((i0 + 2) >> 6)) && (((vw & ~supp) >> ((i0 + 2) & 63)) & 1ull);
        if (__any(a)) supp |= m2;
        a = (tid == ((i0 + 3) >> 6)) && (((vw & ~supp) >> ((i0 + 3) & 63)) & 1ull);
        if (__any(a)) supp |= m3;
      }
    }
    __syncthreads();
  }

  if (tid < 16) keepw[tid] = vw & ~supp;
}

// ---------------------------------------------------------------------------
// Kernel 2: per-(b,c) greedy NMS @ 0.4.
// ---------------------------------------------------------------------------
__global__ __launch_bounds__(1024) void k_nms1(const float* __restrict__ boxes,
                                               const float* __restrict__ score1,
                                               const int* __restrict__ idx1,
                                               int* __restrict__ keep1) {
  __shared__ float4 box4[1024];
  __shared__ float area[1024];
  __shared__ u64 mask[SEGROWS * 16];
  __shared__ u64 validw[16], keepw[16];

  const int slice = blockIdx.x;
  const int b = slice / C_;
  nms_run(score1 + slice * K1_, idx1 + slice * K1_,
          boxes + (size_t)b * N_ * 4, NMS_IOU_F,
          box4, area, mask, validw, keepw);
  __syncthreads();

  const int p = threadIdx.x;
  if (p < K1_)
    keep1[slice * K1_ + p] = (int)((keepw[p >> 6] >> (p & 63)) & 1ull);
}

// ---------------------------------------------------------------------------
// Kernel 3: per-batch top-1000 over the C*K1 survivors (stable, flat-index
// tie-break). Histogram select + adaptive bitonic.
// ---------------------------------------------------------------------------
__global__ __launch_bounds__(256) void k_topk2(const float* __restrict__ score1,
                                               const int* __restrict__ idx1,
                                               const int* __restrict__ keep1,
                                               float* __restrict__ sel_score,
                                               int* __restrict__ sel_cls,
                                               int* __restrict__ sel_orig) {
  const int b = blockIdx.x;
  const int tid = threadIdx.x, bd = blockDim.x;

  __shared__ u32 hist[NBIN];
  __shared__ u64 buf[CAP];
  __shared__ int sh_b1;
  __shared__ u32 sh_base, sh_T, sh_cnt;

  for (int i = tid; i < NBIN; i += bd) hist[i] = 0;
  __syncthreads();
  for (int f = tid; f < N2_; f += bd) {
    if (keep1[b * N2_ + f])
      atomicAdd(&hist[__float_as_uint(score1[b * N2_ + f]) >> 19], 1u);
  }
  __syncthreads();
  if (tid == 0) {
    u32 cum = 0; int b1 = -1; u32 base = 0;
    for (int bin = NBIN - 1; bin >= 0; --bin) {
      cum += hist[bin];
      if (cum >= (u32)K1_) { b1 = bin; base = cum - hist[bin]; break; }
    }
    sh_b1 = b1; sh_base = base;
    if (b1 < 0) sh_T = 0;
  }
  __syncthreads();
  const int b1 = sh_b1;

  if (b1 >= 0) {
    const u32 base = sh_base;
    for (int i = tid; i < NBIN; i += bd) hist[i] = 0;
    __syncthreads();
    for (int f = tid; f < N2_; f += bd) {
      if (keep1[b * N2_ + f]) {
        u32 k = __float_as_uint(score1[b * N2_ + f]);
        if ((int)(k >> 19) == b1) atomicAdd(&hist[(k >> 7) & 0xFFFu], 1u);
      }
    }
    __syncthreads();
    if (tid == 0) {
      u32 cum = base;
      u32 T = ((u32)b1) << 19;
      for (int bin = NBIN - 1; bin >= 0; --bin) {
        cum += hist[bin];
        if (cum >= (u32)K1_) { T = (((u32)b1) << 19) | (((u32)bin) << 7); break; }
      }
      sh_T = T;
    }
    __syncthreads();
  }

  if (tid == 0) sh_cnt = 0;
  __syncthreads();
  const u32 T = sh_T;
  for (int f = tid; f < N2_; f += bd) {
    if (keep1[b * N2_ + f]) {
      u32 k = __float_as_uint(score1[b * N2_ + f]);
      if (k >= T) {
        u32 pos = atomicAdd(&sh_cnt, 1u);
        if (pos < CAP) buf[pos] = ((u64)k << 32) | (u32)(~(u32)f);
      }
    }
  }
  __syncthreads();
  u32 m = sh_cnt; if (m > CAP) m = CAP;
  const u32 n = next_pow2_ge(m, 1024u, (u32)CAP);
  for (u32 i = tid; i < n; i += bd)
    if (i >= m) buf[i] = 0ull;
  __syncthreads();

  for (u32 kk = 2; kk <= n; kk <<= 1) {
    for (u32 j = kk >> 1; j > 0; j >>= 1) {
      for (u32 i = tid; i < n; i += bd) {
        u32 l = i ^ j;
        if (l > i) {
          u64 a = buf[i], bb = buf[l];
          bool desc = ((i & kk) == 0);
          if (desc ? (a < bb) : (a > bb)) { buf[i] = bb; buf[l] = a; }
        }
      }
      __syncthreads();
    }
  }

  for (int p = tid; p < K1_; p += bd) {
    u64 e = buf[p];
    u32 k = (u32)(e >> 32);
    float s; int cls, orig;
    if (k == 0) { s = -1.0f; cls = 0; orig = 0; }
    else {
      s = __uint_as_float(k);
      u32 f = ~(u32)e;
      cls = (int)(f / K1_);
      int slot = (int)(f - (u32)cls * K1_);
      orig = idx1[(b * C_ + cls) * K1_ + slot];
    }
    sel_score[b * K1_ + p] = s;
    sel_cls[b * K1_ + p] = cls;
    sel_orig[b * K1_ + p] = orig;
  }
}

// ---------------------------------------------------------------------------
// Kernel 4: per-batch class-agnostic NMS @ 0.65, stable compaction, output.
// ---------------------------------------------------------------------------
__global__ __launch_bounds__(1024) void k_nms2_out(const float* __restrict__ boxes,
                                                   const float* __restrict__ sel_score,
                                                   const int* __restrict__ sel_cls,
                                                   const int* __restrict__ sel_orig,
                                                   float* __restrict__ out) {
  __shared__ float4 box4[1024];
  __shared__ float area[1024];
  __shared__ u64 mask[SEGROWS * 16];
  __shared__ u64 validw[16], keepw[16];
  __shared__ short ord[K1_];
  __shared__ int lbase[17];
  __shared__ int ordc;

  const int b = blockIdx.x;
  const int tid = threadIdx.x;
  nms_run(sel_score + b * K1_, sel_orig + b * K1_,
          boxes + (size_t)b * N_ * 4, POST_IOU_F,
          box4, area, mask, validw, keepw);
  __syncthreads();

  // parallel stable compaction of kept rows
  if (tid == 0) {
    int acc = 0;
    for (int wdx = 0; wdx < 16; ++wdx) {
      lbase[wdx] = acc;
      acc += __popcll(keepw[wdx]);
    }
    lbase[16] = acc;
    ordc = acc;
  }
  __syncthreads();
  if (tid < 16) {
    u64 m = keepw[tid];
    int base = lbase[tid];
    while (m) {
      int bit = __ffsll((long long)m) - 1;
      ord[base++] = (short)((tid << 6) | bit);
      m &= m - 1;
    }
  }
  __syncthreads();

  for (int t = tid; t < K1_ * 6; t += 1024) out[(size_t)b * K1_ * 6 + t] = 0.0f;
  __syncthreads();

  const int cnt = ordc;
  for (int q = tid; q < cnt; q += 1024) {
    int p = ord[q];
    int oi = sel_orig[b * K1_ + p];
    const float4 bp = *(const float4*)(boxes + ((size_t)b * N_ + oi) * 4);
    float* o = out + ((size_t)b * K1_ + q) * 6;
    o[0] = bp.x; o[1] = bp.y; o[2] = bp.z; o[3] = bp.w;
    o[4] = (float)sel_cls[b * K1_ + p];
    o[5] = sel_score[b * K1_ + p];
  }
}

// ---------------------------------------------------------------------------
extern "C" void kernel_launch(void* const* d_in, const int* in_sizes, int n_in,
                              void* d_out, int out_size, void* d_ws, size_t ws_size,
                              hipStream_t stream) {
  const float* cls = (const float*)d_in[0];    // (8,100000,10) f32
  const float* boxes = (const float*)d_in[1];  // (8,100000,4)  f32
  float* out = (float*)d_out;                  // (8,1000,6)    f32

  char* ws = (char*)d_ws;
  float* score1    = (float*)(ws);                     // 80000 f32
  int*   idx1      = (int*)(ws + 320000);              // 80000 i32
  int*   keep1     = (int*)(ws + 640000);              // 80000 i32
  float* sel_score = (float*)(ws + 960000);            // 8000 f32
  int*   sel_cls   = (int*)(ws + 992000);              // 8000 i32
  int*   sel_orig  = (int*)(ws + 1024000);             // 8000 i32
  u32*   cnt       = (u32*)(ws + 1056000);             // 80 u32
  u32*   flag      = (u32*)(ws + 1056320);             // 80 u32
  u64*   cand      = (u64*)(ws + 1056640);             // 80*2048 u64 = 1.31 MB

  hipLaunchKernelGGL(k_init, dim3(1), dim3(256), 0, stream, cnt, flag);
  hipLaunchKernelGGL(k_compact, dim3(CBLK), dim3(256), 0, stream,
                     cls, cand, cnt, flag);
  hipLaunchKernelGGL(k_sel, dim3(B_ * C_), dim3(256), 0, stream,
                     cand, cnt, flag, score1, idx1);
  hipLaunchKernelGGL(k_topk1_fb, dim3(B_ * C_), dim3(256), 0, stream,
                     cls, flag, score1, idx1);
  hipLaunchKernelGGL(k_nms1, dim3(B_ * C_), dim3(1024), 0, stream,
                     boxes, score1, idx1, keep1);
  hipLaunchKernelGGL(k_topk2, dim3(B_), dim3(256), 0, stream,
                     score1, idx1, keep1, sel_score, sel_cls, sel_orig);
  hipLaunchKernelGGL(k_nms2_out, dim3(B_), dim3(1024), 0, stream,
                     boxes, sel_score, sel_cls, sel_orig, out);
}

// Round 7
// 484.240 us; speedup vs baseline: 4.3225x; 1.4457x over previous
//
#include <hip/hip_runtime.h>
#include <stdint.h>

typedef unsigned int u32;
typedef unsigned long long u64;

#define B_ 8
#define N_ 100000
#define C_ 10
#define K1_ 1000
#define N2_ (C_ * K1_)
#define NBIN 4096
#define CAP 4096       // fallback / topk2 sort capacity
#define CAP_C 2048     // fast-path candidate capacity per slice
#define SEGROWS 256    // NMS mask segment rows (4 segments cover 1000)
#define MIN_CONF_F 0.05f
#define NMS_IOU_F 0.4f
#define POST_IOU_F 0.65f
#define T0_F 0.985f    // conservative fast-path threshold (count ~1500 +/- 38)

#define TOTAL_F4 (B_ * N_ * C_ / 4)  // 2,000,000 float4s
#define CBLK 512                     // compact blocks
#define LCAP 1024                    // per-block local candidate capacity

static __device__ __forceinline__ u32 next_pow2_ge(u32 x, u32 lo, u32 hi) {
  u32 n = lo;
  while (n < x && n < hi) n <<= 1;
  return n;
}

// ---------------------------------------------------------------------------
// Init: zero per-slice counters + fallback flags (ws is poisoned 0xAA).
// ---------------------------------------------------------------------------
__global__ void k_init(u32* __restrict__ cnt, u32* __restrict__ flag) {
  int t = threadIdx.x;
  if (t < B_ * C_) { cnt[t] = 0; flag[t] = 0; }
}

// ---------------------------------------------------------------------------
// Fast path pass 1 (LDS-staged compaction).
// ---------------------------------------------------------------------------
__global__ __launch_bounds__(256) void k_compact(const float* __restrict__ cls,
                                                 u64* __restrict__ cand,
                                                 u32* __restrict__ cnt,
                                                 u32* __restrict__ flag) {
  __shared__ u32 lcnt[B_ * C_];
  __shared__ u32 sbase[B_ * C_];
  __shared__ u32 ltot;
  __shared__ u32 lovf;
  __shared__ u64 ekey[LCAP];
  __shared__ u32 emeta[LCAP];  // (slice<<16) | local_rank

  const int tid = threadIdx.x;
  if (tid < B_ * C_) lcnt[tid] = 0;
  if (tid == 0) { ltot = 0; lovf = 0; }
  __syncthreads();

  const u32 lo = (u32)blockIdx.x * ((TOTAL_F4 + CBLK - 1) / CBLK);
  u32 hi = lo + ((TOTAL_F4 + CBLK - 1) / CBLK);
  if (hi > TOTAL_F4) hi = TOTAL_F4;

  const float4* p4 = (const float4*)cls;
  for (u32 f = lo + tid; f < hi; f += 256) {
    float4 v = p4[f];
    u32 e = f * 4u;
    float vs[4] = {v.x, v.y, v.z, v.w};
#pragma unroll
    for (int j = 0; j < 4; ++j) {
      float s = vs[j];
      if (s >= T0_F) {
        u32 g = e + (u32)j;           // flat index into (B,N,C)
        u32 gi = g / (u32)C_;         // b*N + i
        u32 c = g - gi * (u32)C_;
        u32 bi = gi / (u32)N_;
        u32 i = gi - bi * (u32)N_;
        u32 slice = bi * (u32)C_ + c;
        u32 rank = atomicAdd(&lcnt[slice], 1u);
        u32 pos = atomicAdd(&ltot, 1u);
        if (pos < LCAP) {
          ekey[pos] = ((u64)__float_as_uint(s) << 32) | (u32)(~i);
          emeta[pos] = (slice << 16) | rank;
        } else {
          lovf = 1;
        }
      }
    }
  }
  __syncthreads();

  if (lovf) {
    if (tid < B_ * C_) flag[tid] = 1;
  }
  if (tid < B_ * C_) {
    u32 n = lcnt[tid];
    sbase[tid] = n ? atomicAdd(&cnt[tid], n) : 0u;
  }
  __syncthreads();

  u32 tot = ltot;
  if (tot > LCAP) tot = LCAP;
  for (u32 p = tid; p < tot; p += 256) {
    u32 mta = emeta[p];
    u32 slice = mta >> 16;
    u32 rank = mta & 0xFFFFu;
    u32 dst = sbase[slice] + rank;
    if (dst < CAP_C) cand[(size_t)slice * CAP_C + dst] = ekey[p];
  }
}

// ---------------------------------------------------------------------------
// Bitonic sort step set for 1024 threads: one exchange per thread per step.
// i = ((t & ~(j-1)) << 1) | (t & (j-1)); partner = i | j  (same pairs and
// directions as the canonical i-loop form).
// ---------------------------------------------------------------------------
__device__ __forceinline__ void bitonic_sort_desc(u64* buf, u32 n, int tid,
                                                  int bd) {
  for (u32 kk = 2; kk <= n; kk <<= 1) {
    for (u32 j = kk >> 1; j > 0; j >>= 1) {
      for (u32 t = tid; t < (n >> 1); t += bd) {
        u32 i = ((t & ~(j - 1)) << 1) | (t & (j - 1));
        u32 l = i | j;
        u64 a = buf[i], bb = buf[l];
        bool desc = ((i & kk) == 0);
        if (desc ? (a < bb) : (a > bb)) { buf[i] = bb; buf[l] = a; }
      }
      __syncthreads();
    }
  }
}

// ---------------------------------------------------------------------------
// Fast path pass 2: per-slice adaptive bitonic sort, emit top 1000.
// 1024 threads.
// ---------------------------------------------------------------------------
__global__ __launch_bounds__(1024) void k_sel(const u64* __restrict__ cand,
                                              const u32* __restrict__ cnt,
                                              u32* __restrict__ flag,
                                              float* __restrict__ score1,
                                              int* __restrict__ idx1) {
  const int slice = blockIdx.x;
  const int tid = threadIdx.x;
  __shared__ u64 buf[CAP_C];

  u32 m = cnt[slice];
  if (flag[slice] || m < (u32)K1_ || m > (u32)CAP_C) {
    if (tid == 0) flag[slice] = 1;
    return;
  }
  const u32 n = next_pow2_ge(m, 1024u, (u32)CAP_C);

  for (u32 i = tid; i < n; i += 1024)
    buf[i] = (i < m) ? cand[(size_t)slice * CAP_C + i] : 0ull;
  __syncthreads();

  bitonic_sort_desc(buf, n, tid, 1024);

  if (tid < K1_) {
    u64 e = buf[tid];
    u32 k = (u32)(e >> 32);
    score1[slice * K1_ + tid] = __uint_as_float(k);
    idx1[slice * K1_ + tid] = (int)(~(u32)e);
  }
}

// ---------------------------------------------------------------------------
// Fallback (exact, slow) per-slice top-1000 — only runs for flagged slices.
// ---------------------------------------------------------------------------
__global__ __launch_bounds__(256) void k_topk1_fb(const float* __restrict__ cls,
                                                  const u32* __restrict__ flag,
                                                  float* __restrict__ score1,
                                                  int* __restrict__ idx1) {
  const int slice = blockIdx.x;
  if (!flag[slice]) return;
  const int b = slice / C_, c = slice % C_;
  const int tid = threadIdx.x, bd = blockDim.x;

  __shared__ u32 hist[NBIN];
  __shared__ u64 buf[CAP];
  __shared__ int sh_b1;
  __shared__ u32 sh_base, sh_T, sh_cnt;

  for (int i = tid; i < NBIN; i += bd) hist[i] = 0;
  __syncthreads();
  for (int i = tid; i < N_; i += bd) {
    float s = cls[((size_t)b * N_ + i) * C_ + c];
    if (s >= MIN_CONF_F) atomicAdd(&hist[__float_as_uint(s) >> 19], 1u);
  }
  __syncthreads();
  if (tid == 0) {
    u32 cum = 0; int b1 = -1; u32 base = 0;
    for (int bin = NBIN - 1; bin >= 0; --bin) {
      cum += hist[bin];
      if (cum >= (u32)K1_) { b1 = bin; base = cum - hist[bin]; break; }
    }
    sh_b1 = b1; sh_base = base;
    if (b1 < 0) sh_T = 0;
  }
  __syncthreads();
  const int b1 = sh_b1;

  if (b1 >= 0) {
    const u32 base = sh_base;
    for (int i = tid; i < NBIN; i += bd) hist[i] = 0;
    __syncthreads();
    for (int i = tid; i < N_; i += bd) {
      float s = cls[((size_t)b * N_ + i) * C_ + c];
      if (s >= MIN_CONF_F) {
        u32 k = __float_as_uint(s);
        if ((int)(k >> 19) == b1) atomicAdd(&hist[(k >> 7) & 0xFFFu], 1u);
      }
    }
    __syncthreads();
    if (tid == 0) {
      u32 cum = base;
      u32 T = ((u32)b1) << 19;
      for (int bin = NBIN - 1; bin >= 0; --bin) {
        cum += hist[bin];
        if (cum >= (u32)K1_) { T = (((u32)b1) << 19) | (((u32)bin) << 7); break; }
      }
      sh_T = T;
    }
    __syncthreads();
  }

  if (tid == 0) sh_cnt = 0;
  __syncthreads();
  const u32 T = sh_T;
  for (int i = tid; i < N_; i += bd) {
    float s = cls[((size_t)b * N_ + i) * C_ + c];
    if (s >= MIN_CONF_F) {
      u32 k = __float_as_uint(s);
      if (k >= T) {
        u32 pos = atomicAdd(&sh_cnt, 1u);
        if (pos < CAP) buf[pos] = ((u64)k << 32) | (u32)(~(u32)i);
      }
    }
  }
  __syncthreads();
  u32 m = sh_cnt; if (m > CAP) m = CAP;
  for (int i = tid; i < CAP; i += bd)
    if ((u32)i >= m) buf[i] = 0ull;
  __syncthreads();

  for (u32 kk = 2; kk <= CAP; kk <<= 1) {
    for (u32 j = kk >> 1; j > 0; j >>= 1) {
      for (u32 i = tid; i < CAP; i += bd) {
        u32 l = i ^ j;
        if (l > i) {
          u64 a = buf[i], bb = buf[l];
          bool desc = ((i & kk) == 0);
          if (desc ? (a < bb) : (a > bb)) { buf[i] = bb; buf[l] = a; }
        }
      }
      __syncthreads();
    }
  }

  for (int p = tid; p < K1_; p += bd) {
    u64 e = buf[p];
    u32 k = (u32)(e >> 32);
    float s; int oi;
    if (k == 0) { s = -1.0f; oi = 0; }
    else { s = __uint_as_float(k); oi = (int)(~(u32)e); }
    score1[slice * K1_ + p] = s;
    idx1[slice * K1_ + p] = oi;
  }
}

// ---------------------------------------------------------------------------
// NMS core v3 (validated R6): lane-per-row tiled build + single-wave scan.
// ---------------------------------------------------------------------------
__device__ __forceinline__ void nms_run(const float* __restrict__ scores,
                                        const int* __restrict__ origs,
                                        const float* __restrict__ boxesB,
                                        float thr,
                                        float4* box4, float* area,
                                        u64* mask, u64* validw, u64* keepw) {
  const int tid = threadIdx.x;
  const int wave = tid >> 6, lane = tid & 63;

  {
    const int p = tid;
    float s = (p < K1_) ? scores[p] : -1.0f;
    bool v = (s >= MIN_CONF_F);
    float cx = 0.f, cy = 0.f, w = 0.f, h = 0.f;
    if (v) {
      const float4 bp = *(const float4*)(boxesB + (size_t)origs[p] * 4);
      cx = bp.x; cy = bp.y; w = bp.z; h = bp.w;
    }
    float y1 = cy - h * 0.5f, x1 = cx - w * 0.5f;
    float y2 = cy + h * 0.5f, x2 = cx + w * 0.5f;
    box4[p] = make_float4(y1, x1, y2, x2);
    area[p] = (y2 - y1) * (x2 - x1);
    u64 mb = __ballot(v);
    if (lane == 0) validw[wave] = mb;
  }
  __syncthreads();

  const float cf = thr;
  const float cnext = __uint_as_float(__float_as_uint(cf) + 1u);
  const double M = ((double)cf + (double)cnext) * 0.5;
  const bool strict = ((__float_as_uint(cf) & 1u) == 0u);

  u64 vw = validw[tid & 15];
  u64 supp = 0;

  for (int seg = 0; seg < 4; ++seg) {
    const int ibase = seg * SEGROWS;
    const int lim = (K1_ - ibase < SEGROWS) ? (K1_ - ibase) : SEGROWS;

    for (int t = wave; t < 64; t += 16) {
      const int rtl = t >> 4;
      const int w = t & 15;
      const int il = (rtl << 6) | lane;
      const int i = ibase + il;
      const int rtg = (ibase >> 6) + rtl;
      u64 m = 0;
      if (w >= rtg) {
        const float4 ib = box4[i];
        const float ia = area[i];
        const float4* jcol = &box4[w << 6];
        const float* jare = &area[w << 6];
        u32 mhi = 0, mlo = 0;
#pragma unroll 8
        for (int j = 63; j >= 32; --j) {
          float4 jb = jcol[j];
          float ja = jare[j];
          float ih = fminf(ib.z, jb.z) - fmaxf(ib.x, jb.x); ih = fmaxf(ih, 0.0f);
          float iw_ = fminf(ib.w, jb.w) - fmaxf(ib.y, jb.y); iw_ = fmaxf(iw_, 0.0f);
          float inter = ih * iw_;
          float den = fmaxf((ia + ja) - inter, 1e-8f);
          bool p_ = strict ? ((double)inter > M * (double)den)
                           : ((double)inter >= M * (double)den);
          mhi = (mhi << 1) | (p_ ? 1u : 0u);
        }
#pragma unroll 8
        for (int j = 31; j >= 0; --j) {
          float4 jb = jcol[j];
          float ja = jare[j];
          float ih = fminf(ib.z, jb.z) - fmaxf(ib.x, jb.x); ih = fmaxf(ih, 0.0f);
          float iw_ = fminf(ib.w, jb.w) - fmaxf(ib.y, jb.y); iw_ = fmaxf(iw_, 0.0f);
          float inter = ih * iw_;
          float den = fmaxf((ia + ja) - inter, 1e-8f);
          bool p_ = strict ? ((double)inter > M * (double)den)
                           : ((double)inter >= M * (double)den);
          mlo = (mlo << 1) | (p_ ? 1u : 0u);
        }
        m = ((u64)mhi << 32) | (u64)mlo;
        if (w == rtg)
          m &= (lane == 63) ? 0ull : (~0ull << (lane + 1));
      }
      mask[il * 16 + (w ^ (il & 15))] = m;
    }
    __syncthreads();

    if (tid < 64) {
      const int l = tid & 15;
      u64 r0 = mask[0 * 16 + (l ^ 0)];
      u64 r1 = mask[1 * 16 + (l ^ 1)];
      u64 r2 = mask[2 * 16 + (l ^ 2)];
      u64 r3 = mask[3 * 16 + (l ^ 3)];
      for (int il = 0; il < lim; il += 4) {
        const int i0 = ibase + il;
        const int n0 = (il + 4 < lim) ? il + 4 : il;
        const int n1 = (il + 5 < lim) ? il + 5 : il;
        const int n2 = (il + 6 < lim) ? il + 6 : il;
        const int n3 = (il + 7 < lim) ? il + 7 : il;
        u64 m0 = r0, m1 = r1, m2 = r2, m3 = r3;
        r0 = mask[n0 * 16 + (l ^ (n0 & 15))];
        r1 = mask[n1 * 16 + (l ^ (n1 & 15))];
        r2 = mask[n2 * 16 + (l ^ (n2 & 15))];
        r3 = mask[n3 * 16 + (l ^ (n3 & 15))];
        bool a;
        a = (tid == (i0 >> 6)) && (((vw & ~supp) >> (i0 & 63)) & 1ull);
        if (__any(a)) supp |= m0;
        a = (tid == ((i0 + 1) >> 6)) && (((vw & ~supp) >> ((i0 + 1) & 63)) & 1ull);
        if (__any(a)) supp |= m1;
        a = (tid == ((i0 + 2) >> 6)) && (((vw & ~supp) >> ((i0 + 2) & 63)) & 1ull);
        if (__any(a)) supp |= m2;
        a = (tid == ((i0 + 3) >> 6)) && (((vw & ~supp) >> ((i0 + 3) & 63)) & 1ull);
        if (__any(a)) supp |= m3;
      }
    }
    __syncthreads();
  }

  if (tid < 16) keepw[tid] = vw & ~supp;
}

// ---------------------------------------------------------------------------
// Kernel 2: per-(b,c) greedy NMS @ 0.4.
// ---------------------------------------------------------------------------
__global__ __launch_bounds__(1024) void k_nms1(const float* __restrict__ boxes,
                                               const float* __restrict__ score1,
                                               const int* __restrict__ idx1,
                                               int* __restrict__ keep1) {
  __shared__ float4 box4[1024];
  __shared__ float area[1024];
  __shared__ u64 mask[SEGROWS * 16];
  __shared__ u64 validw[16], keepw[16];

  const int slice = blockIdx.x;
  const int b = slice / C_;
  nms_run(score1 + slice * K1_, idx1 + slice * K1_,
          boxes + (size_t)b * N_ * 4, NMS_IOU_F,
          box4, area, mask, validw, keepw);
  __syncthreads();

  const int p = threadIdx.x;
  if (p < K1_)
    keep1[slice * K1_ + p] = (int)((keepw[p >> 6] >> (p & 63)) & 1ull);
}

// ---------------------------------------------------------------------------
// Parallel boundary-bin select over a 4096-bin LDS histogram (1024 threads,
// 4 bins/thread). Finds the unique bin with base+suf[bin] >= K and
// base+suf[bin+1] < K (== "first bin from the top with cum >= K").
// out_bin = -1 if base+total < K. out_next = base + suf[bin+1].
// Caller must have hist filled + synced; all threads must call.
// ---------------------------------------------------------------------------
__device__ __forceinline__ void suffix_select(const u32* __restrict__ hist,
                                              u32* __restrict__ aux,
                                              u32 base, u32 K,
                                              int* out_bin, u32* out_next) {
  const int t = threadIdx.x;  // 1024
  u32 h0 = hist[4 * t], h1 = hist[4 * t + 1];
  u32 h2 = hist[4 * t + 2], h3 = hist[4 * t + 3];
  aux[t] = h0 + h1 + h2 + h3;
  __syncthreads();
  for (int off = 1; off < 1024; off <<= 1) {
    u32 v = aux[t] + ((t + off < 1024) ? aux[t + off] : 0u);
    __syncthreads();
    aux[t] = v;
    __syncthreads();
  }
  if (t == 0 && base + aux[0] < K) { *out_bin = -1; *out_next = base; }
  u32 up = (t < 1023) ? aux[t + 1] : 0u;
  u32 s3 = h3 + up;
  u32 s2 = h2 + s3;
  u32 s1 = h1 + s2;
  u32 s0 = h0 + s1;
  u32 c0 = base + s0, c1 = base + s1, c2 = base + s2, c3 = base + s3;
  u32 c4 = base + up;
  if (c0 >= K && c1 < K) { *out_bin = 4 * t;     *out_next = c1; }
  if (c1 >= K && c2 < K) { *out_bin = 4 * t + 1; *out_next = c2; }
  if (c2 >= K && c3 < K) { *out_bin = 4 * t + 2; *out_next = c3; }
  if (c3 >= K && c4 < K) { *out_bin = 4 * t + 3; *out_next = c4; }
  __syncthreads();
}

// ---------------------------------------------------------------------------
// Kernel 3: per-batch top-1000 over the C*K1 survivors (stable, flat-index
// tie-break). Parallel histogram select + 1024-thread adaptive bitonic.
// ---------------------------------------------------------------------------
__global__ __launch_bounds__(1024) void k_topk2(const float* __restrict__ score1,
                                                const int* __restrict__ idx1,
                                                const int* __restrict__ keep1,
                                                float* __restrict__ sel_score,
                                                int* __restrict__ sel_cls,
                                                int* __restrict__ sel_orig) {
  const int b = blockIdx.x;
  const int tid = threadIdx.x;

  __shared__ u32 hist[NBIN];
  __shared__ u32 aux[1024];
  __shared__ u64 buf[CAP];
  __shared__ int sh_bin;
  __shared__ u32 sh_next;
  __shared__ u32 sh_T, sh_cnt;

  // ---- level-1 histogram on bits[30:19] ----
  for (int i = tid; i < NBIN; i += 1024) hist[i] = 0;
  __syncthreads();
  for (int f = tid; f < N2_; f += 1024) {
    if (keep1[b * N2_ + f])
      atomicAdd(&hist[__float_as_uint(score1[b * N2_ + f]) >> 19], 1u);
  }
  __syncthreads();
  suffix_select(hist, aux, 0u, (u32)K1_, &sh_bin, &sh_next);
  const int b1 = sh_bin;
  const u32 base = sh_next;

  if (b1 >= 0) {
    // ---- level-2 histogram on bits[18:7] within boundary bin ----
    for (int i = tid; i < NBIN; i += 1024) hist[i] = 0;
    if (tid == 0) sh_bin = -2;  // sentinel (level-2 always finds, but be safe)
    __syncthreads();
    for (int f = tid; f < N2_; f += 1024) {
      if (keep1[b * N2_ + f]) {
        u32 k = __float_as_uint(score1[b * N2_ + f]);
        if ((int)(k >> 19) == b1) atomicAdd(&hist[(k >> 7) & 0xFFFu], 1u);
      }
    }
    __syncthreads();
    suffix_select(hist, aux, base, (u32)K1_, &sh_bin, &sh_next);
    if (tid == 0) {
      int b2 = sh_bin;
      sh_T = (b2 >= 0) ? ((((u32)b1) << 19) | (((u32)b2) << 7))
                       : (((u32)b1) << 19);
    }
  } else {
    if (tid == 0) sh_T = 0;  // fewer than K1 valid -> take all
  }
  if (tid == 0) sh_cnt = 0;
  __syncthreads();

  // ---- compact all candidates with key >= T ----
  const u32 T = sh_T;
  for (int f = tid; f < N2_; f += 1024) {
    if (keep1[b * N2_ + f]) {
      u32 k = __float_as_uint(score1[b * N2_ + f]);
      if (k >= T) {
        u32 pos = atomicAdd(&sh_cnt, 1u);
        if (pos < CAP) buf[pos] = ((u64)k << 32) | (u32)(~(u32)f);
      }
    }
  }
  __syncthreads();
  u32 m = sh_cnt; if (m > CAP) m = CAP;
  const u32 n = next_pow2_ge(m, 1024u, (u32)CAP);
  for (u32 i = tid; i < n; i += 1024)
    if (i >= m) buf[i] = 0ull;
  __syncthreads();

  bitonic_sort_desc(buf, n, tid, 1024);

  if (tid < K1_) {
    u64 e = buf[tid];
    u32 k = (u32)(e >> 32);
    float s; int cls, orig;
    if (k == 0) { s = -1.0f; cls = 0; orig = 0; }
    else {
      s = __uint_as_float(k);
      u32 f = ~(u32)e;
      cls = (int)(f / K1_);
      int slot = (int)(f - (u32)cls * K1_);
      orig = idx1[(b * C_ + cls) * K1_ + slot];
    }
    sel_score[b * K1_ + tid] = s;
    sel_cls[b * K1_ + tid] = cls;
    sel_orig[b * K1_ + tid] = orig;
  }
}

// ---------------------------------------------------------------------------
// Kernel 4: per-batch class-agnostic NMS @ 0.65, stable compaction, output.
// ---------------------------------------------------------------------------
__global__ __launch_bounds__(1024) void k_nms2_out(const float* __restrict__ boxes,
                                                   const float* __restrict__ sel_score,
                                                   const int* __restrict__ sel_cls,
                                                   const int* __restrict__ sel_orig,
                                                   float* __restrict__ out) {
  __shared__ float4 box4[1024];
  __shared__ float area[1024];
  __shared__ u64 mask[SEGROWS * 16];
  __shared__ u64 validw[16], keepw[16];
  __shared__ short ord[K1_];
  __shared__ int lbase[17];
  __shared__ int ordc;

  const int b = blockIdx.x;
  const int tid = threadIdx.x;
  nms_run(sel_score + b * K1_, sel_orig + b * K1_,
          boxes + (size_t)b * N_ * 4, POST_IOU_F,
          box4, area, mask, validw, keepw);
  __syncthreads();

  if (tid == 0) {
    int acc = 0;
    for (int wdx = 0; wdx < 16; ++wdx) {
      lbase[wdx] = acc;
      acc += __popcll(keepw[wdx]);
    }
    lbase[16] = acc;
    ordc = acc;
  }
  __syncthreads();
  if (tid < 16) {
    u64 m = keepw[tid];
    int base = lbase[tid];
    while (m) {
      int bit = __ffsll((long long)m) - 1;
      ord[base++] = (short)((tid << 6) | bit);
      m &= m - 1;
    }
  }
  __syncthreads();

  for (int t = tid; t < K1_ * 6; t += 1024) out[(size_t)b * K1_ * 6 + t] = 0.0f;
  __syncthreads();

  const int cnt = ordc;
  for (int q = tid; q < cnt; q += 1024) {
    int p = ord[q];
    int oi = sel_orig[b * K1_ + p];
    const float4 bp = *(const float4*)(boxes + ((size_t)b * N_ + oi) * 4);
    float* o = out + ((size_t)b * K1_ + q) * 6;
    o[0] = bp.x; o[1] = bp.y; o[2] = bp.z; o[3] = bp.w;
    o[4] = (float)sel_cls[b * K1_ + p];
    o[5] = sel_score[b * K1_ + p];
  }
}

// ---------------------------------------------------------------------------
extern "C" void kernel_launch(void* const* d_in, const int* in_sizes, int n_in,
                              void* d_out, int out_size, void* d_ws, size_t ws_size,
                              hipStream_t stream) {
  const float* cls = (const float*)d_in[0];    // (8,100000,10) f32
  const float* boxes = (const float*)d_in[1];  // (8,100000,4)  f32
  float* out = (float*)d_out;                  // (8,1000,6)    f32

  char* ws = (char*)d_ws;
  float* score1    = (float*)(ws);                     // 80000 f32
  int*   idx1      = (int*)(ws + 320000);              // 80000 i32
  int*   keep1     = (int*)(ws + 640000);              // 80000 i32
  float* sel_score = (float*)(ws + 960000);            // 8000 f32
  int*   sel_cls   = (int*)(ws + 992000);              // 8000 i32
  int*   sel_orig  = (int*)(ws + 1024000);             // 8000 i32
  u32*   cnt       = (u32*)(ws + 1056000);             // 80 u32
  u32*   flag      = (u32*)(ws + 1056320);             // 80 u32
  u64*   cand      = (u64*)(ws + 1056640);             // 80*2048 u64 = 1.31 MB

  hipLaunchKernelGGL(k_init, dim3(1), dim3(256), 0, stream, cnt, flag);
  hipLaunchKernelGGL(k_compact, dim3(CBLK), dim3(256), 0, stream,
                     cls, cand, cnt, flag);
  hipLaunchKernelGGL(k_sel, dim3(B_ * C_), dim3(1024), 0, stream,
                     cand, cnt, flag, score1, idx1);
  hipLaunchKernelGGL(k_topk1_fb, dim3(B_ * C_), dim3(256), 0, stream,
                     cls, flag, score1, idx1);
  hipLaunchKernelGGL(k_nms1, dim3(B_ * C_), dim3(1024), 0, stream,
                     boxes, score1, idx1, keep1);
  hipLaunchKernelGGL(k_topk2, dim3(B_), dim3(1024), 0, stream,
                     score1, idx1, keep1, sel_score, sel_cls, sel_orig);
  hipLaunchKernelGGL(k_nms2_out, dim3(B_), dim3(1024), 0, stream,
                     boxes, sel_score, sel_cls, sel_orig, out);
}